// Round 5
// baseline (2946.454 us; speedup 1.0000x reference)
//
#include <hip/hip_runtime.h>
#include <hip/hip_bf16.h>

#define N_NODES 100000
#define N_EDGES 1600000
#define D 128
#define NBUCK 1563   // ceil(N_NODES / 64): 64 dst nodes per bucket

typedef unsigned int  uint4n  __attribute__((ext_vector_type(4)));
typedef float         float4n __attribute__((ext_vector_type(4)));
typedef _Float16      half8n  __attribute__((ext_vector_type(8)));
typedef _Float16      half4n  __attribute__((ext_vector_type(4)));
typedef _Float16      half2n  __attribute__((ext_vector_type(2)));

// ---------------- bucket build (coarse counting partition by dst>>6) ----------------

__global__ void k_zero(int* __restrict__ p, int n) {
    int i = blockIdx.x * 256 + threadIdx.x;
    if (i < n) p[i] = 0;
}

__global__ void k_histb(const int* __restrict__ dst, int* __restrict__ bcnt, int E) {
    int i = blockIdx.x * 256 + threadIdx.x;
    if (i < E) atomicAdd(&bcnt[dst[i] >> 6], 1);
}

// Single-block exclusive scan over NBUCK bucket counts -> boff & cursor.
__global__ void k_scanb(const int* __restrict__ bcnt, int* __restrict__ boff,
                        int* __restrict__ cursor) {
    __shared__ int tmp[256];
    int tid = threadIdx.x;
    int carry = 0;
    for (int c = 0; c < (NBUCK + 255) / 256; c++) {
        int i = c * 256 + tid;
        int v = (i < NBUCK) ? bcnt[i] : 0;
        tmp[tid] = v;
        __syncthreads();
        int run = v;
        for (int off = 1; off < 256; off <<= 1) {
            int t = (tid >= off) ? tmp[tid - off] : 0;
            __syncthreads();
            run += t;
            tmp[tid] = run;
            __syncthreads();
        }
        int excl = carry + run - v;
        if (i < NBUCK) { boff[i] = excl; cursor[i] = excl; }
        int tot = tmp[255];
        __syncthreads();
        carry += tot;
    }
    if (tid == 0) boff[NBUCK] = N_EDGES;
}

// Append each edge to its bucket. Payload: (src<<6 | dst&63, weight) = 8B.
__global__ void k_scatb(const int* __restrict__ src, const int* __restrict__ dst,
                        const float* __restrict__ ew, int* __restrict__ cursor,
                        int2* __restrict__ ebuf, int E) {
    int i = blockIdx.x * 256 + threadIdx.x;
    if (i < E) {
        int d = dst[i];
        int p = atomicAdd(&cursor[d >> 6], 1);
        ebuf[p] = make_int2((src[i] << 6) | (d & 63), __float_as_int(ew[i]));
    }
}

// ---------------- GEMM: H[n x 128](fp16) = X[n x 128] @ W[128 x 128] ----------------
template<bool XF16>
__global__ __launch_bounds__(256) void k_gemm(const void* __restrict__ Xv,
                                              const float* __restrict__ W,
                                              _Float16* __restrict__ H, int n) {
    __shared__ float sW[128][64];   // sW[k][c]
    __shared__ float sX[128][64];   // sX[k][r]
    int rows0 = blockIdx.x * 64;
    int cols0 = blockIdx.y * 64;
    int tid = threadIdx.x;

    for (int i = 0; i < 8; i++) {
        int L4 = i * 256 + tid;
        int k  = L4 >> 4;
        int c4 = L4 & 15;
        float4 w4 = *(const float4*)&W[k * 128 + cols0 + c4 * 4];
        *(float4*)&sW[k][c4 * 4] = w4;
    }
    {
        int r  = tid >> 2;
        int kq = (tid & 3) * 32;
        int rg = rows0 + r;
        if (XF16) {
            const _Float16* Xh = (const _Float16*)Xv + (size_t)rg * 128;
            for (int j = 0; j < 4; j++) {
                half8n v = half8n(0);
                if (rg < n) v = *(const half8n*)(Xh + kq + j * 8);
                int kk = kq + j * 8;
                #pragma unroll
                for (int q = 0; q < 8; q++) sX[kk + q][r] = (float)v[q];
            }
        } else {
            const float* Xf = (const float*)Xv + (size_t)rg * 128;
            for (int j = 0; j < 8; j++) {
                float4 xv = make_float4(0.f, 0.f, 0.f, 0.f);
                if (rg < n) xv = *(const float4*)(Xf + kq + j * 4);
                int kk = kq + j * 4;
                sX[kk + 0][r] = xv.x;
                sX[kk + 1][r] = xv.y;
                sX[kk + 2][r] = xv.z;
                sX[kk + 3][r] = xv.w;
            }
        }
    }
    __syncthreads();

    int tx = tid & 15;
    int ty = tid >> 4;
    float acc[4][4] = {};
    #pragma unroll 8
    for (int k = 0; k < 128; k++) {
        float4 a = *(const float4*)&sX[k][ty * 4];
        float4 b = *(const float4*)&sW[k][tx * 4];
        acc[0][0] += a.x * b.x; acc[0][1] += a.x * b.y; acc[0][2] += a.x * b.z; acc[0][3] += a.x * b.w;
        acc[1][0] += a.y * b.x; acc[1][1] += a.y * b.y; acc[1][2] += a.y * b.z; acc[1][3] += a.y * b.w;
        acc[2][0] += a.z * b.x; acc[2][1] += a.z * b.y; acc[2][2] += a.z * b.z; acc[2][3] += a.z * b.w;
        acc[3][0] += a.w * b.x; acc[3][1] += a.w * b.y; acc[3][2] += a.w * b.z; acc[3][3] += a.w * b.w;
    }
    for (int i = 0; i < 4; i++) {
        int row = rows0 + ty * 4 + i;
        if (row < n) {
            half4n o;
            o[0] = (_Float16)acc[i][0]; o[1] = (_Float16)acc[i][1];
            o[2] = (_Float16)acc[i][2]; o[3] = (_Float16)acc[i][3];
            *(half4n*)&H[(size_t)row * 128 + cols0 + tx * 4] = o;
        }
    }
}

// ---------------- Aggregation: one workgroup per bucket of 64 dst nodes ----------------
// acc[64][128] f32 in LDS; each wave processes one edge: 64 lanes gather the
// 256B fp16 row (4B/lane = 2 cols), scale, atomicAdd into LDS (2-way bank = free).
template<bool OUTF16>
__global__ __launch_bounds__(512) void k_aggb(const _Float16* __restrict__ H,
                                              const int* __restrict__ boff,
                                              const int2* __restrict__ ebuf,
                                              void* __restrict__ outv) {
    __shared__ float acc[64][128];   // 32KB
    int tid = threadIdx.x;
    int b   = blockIdx.x;

    float4n* accv = (float4n*)&acc[0][0];
    float4n z = {0.f, 0.f, 0.f, 0.f};
    #pragma unroll
    for (int i = 0; i < 4; i++) accv[i * 512 + tid] = z;
    __syncthreads();

    int e0 = boff[b], e1 = boff[b + 1];
    int wv = tid >> 6, lane = tid & 63;
    int base = lane * 2;

    for (int e = e0 + wv; e < e1; e += 16) {     // 8 waves x 2-deep unroll
        int2 eda = ebuf[e];
        bool hb = (e + 8) < e1;                   // wave-uniform
        int2 edb = hb ? ebuf[e + 8] : eda;
        half2n va = *(const half2n*)(H + (size_t)(eda.x >> 6) * 128 + base);
        half2n vb = *(const half2n*)(H + (size_t)(edb.x >> 6) * 128 + base);
        float wa = __int_as_float(eda.y);
        int   ra = eda.x & 63;
        atomicAdd(&acc[ra][base],     wa * (float)va.x);
        atomicAdd(&acc[ra][base + 1], wa * (float)va.y);
        if (hb) {
            float wb = __int_as_float(edb.y);
            int   rb = edb.x & 63;
            atomicAdd(&acc[rb][base],     wb * (float)vb.x);
            atomicAdd(&acc[rb][base + 1], wb * (float)vb.y);
        }
    }
    __syncthreads();

    // tanh + writeout: 8 threads per dst row, 16 cols each.
    int r = tid >> 3, c0 = (tid & 7) * 16;
    int node = b * 64 + r;
    if (node < N_NODES) {
        if (OUTF16) {
            half8n h8a, h8b;
            #pragma unroll
            for (int j = 0; j < 8; j++) h8a[j] = (_Float16)tanhf(acc[r][c0 + j]);
            #pragma unroll
            for (int j = 0; j < 8; j++) h8b[j] = (_Float16)tanhf(acc[r][c0 + 8 + j]);
            _Float16* o = (_Float16*)outv + (size_t)node * 128 + c0;
            *(half8n*)o = h8a;
            *(half8n*)(o + 8) = h8b;
        } else {
            float* o = (float*)outv + (size_t)node * 128 + c0;
            #pragma unroll
            for (int q = 0; q < 4; q++) {
                float4n f4;
                f4.x = tanhf(acc[r][c0 + q * 4 + 0]);
                f4.y = tanhf(acc[r][c0 + q * 4 + 1]);
                f4.z = tanhf(acc[r][c0 + q * 4 + 2]);
                f4.w = tanhf(acc[r][c0 + q * 4 + 3]);
                __builtin_nontemporal_store(f4, (float4n*)(o + q * 4));
            }
        }
    }
}

// ---------------- launch ----------------

extern "C" void kernel_launch(void* const* d_in, const int* in_sizes, int n_in,
                              void* d_out, int out_size, void* d_ws, size_t ws_size,
                              hipStream_t stream) {
    const float* x    = (const float*)d_in[0];
    const int*   esrc = (const int*)d_in[1];
    const int*   edst = (const int*)d_in[2];
    const float* ew   = (const float*)d_in[3];
    const float* W1   = (const float*)d_in[4];
    const float* W2   = (const float*)d_in[5];
    float* out = (float*)d_out;

    // Workspace layout (~64 MB):
    _Float16* hbuf = (_Float16*)d_ws;                      // N*D fp16 (25.6 MB)
    _Float16* act1 = hbuf + (size_t)N_NODES * D;           // N*D fp16 (25.6 MB)
    int2* ebuf     = (int2*)(act1 + (size_t)N_NODES * D);  // E int2 (12.8 MB), 8B-aligned
    int*  bcnt     = (int*)(ebuf + N_EDGES);               // NBUCK
    int*  boff     = bcnt + NBUCK;                         // NBUCK+1
    int*  cursor   = boff + (NBUCK + 1);                   // NBUCK
    (void)ws_size; (void)in_sizes; (void)n_in; (void)out_size;

    // --- bucket build (graph identical for both layers) ---
    k_zero <<<(NBUCK + 255) / 256, 256, 0, stream>>>(bcnt, NBUCK);
    k_histb<<<(N_EDGES + 255) / 256, 256, 0, stream>>>(edst, bcnt, N_EDGES);
    k_scanb<<<1, 256, 0, stream>>>(bcnt, boff, cursor);
    k_scatb<<<(N_EDGES + 255) / 256, 256, 0, stream>>>(esrc, edst, ew, cursor, ebuf, N_EDGES);

    dim3 gg((N_NODES + 63) / 64, 2);

    // --- layer 1 ---
    k_gemm<false><<<gg, 256, 0, stream>>>(x, W1, hbuf, N_NODES);
    k_aggb<true><<<NBUCK, 512, 0, stream>>>(hbuf, boff, ebuf, act1);
    // --- layer 2 ---
    k_gemm<true><<<gg, 256, 0, stream>>>(act1, W2, hbuf, N_NODES);
    k_aggb<false><<<NBUCK, 512, 0, stream>>>(hbuf, boff, ebuf, out);
}

// Round 6
// 319.874 us; speedup vs baseline: 9.2113x; 9.2113x over previous
//
#include <hip/hip_runtime.h>
#include <hip/hip_bf16.h>

#define N_NODES 100000
#define N_EDGES 1600000
#define D 128
#define BSZ 128                         // dst nodes per bucket
#define NBUCK 782                       // ceil(N_NODES / BSZ)
#define EPW 8192                        // edges per WG in hist/scatter
#define NWG1 ((N_EDGES + EPW - 1) / EPW)  // 196
#define CAP 4096                        // LDS edge staging per bucket (mean 2048)

typedef unsigned int  uint4n  __attribute__((ext_vector_type(4)));
typedef float         float4n __attribute__((ext_vector_type(4)));
typedef _Float16      half8n  __attribute__((ext_vector_type(8)));
typedef _Float16      half4n  __attribute__((ext_vector_type(4)));

// ---------------- stage 0: bucket histogram (LDS-staged, low contention) ----------------

__global__ void k_zero(int* __restrict__ p, int n) {
    int i = blockIdx.x * 256 + threadIdx.x;
    if (i < n) p[i] = 0;
}

__global__ __launch_bounds__(256) void k_hist1(const int* __restrict__ dst,
                                               int* __restrict__ bcnt) {
    __shared__ int h[NBUCK];
    for (int i = threadIdx.x; i < NBUCK; i += 256) h[i] = 0;
    __syncthreads();
    int base = blockIdx.x * EPW;
    int end  = min(base + EPW, N_EDGES);
    for (int i = base + threadIdx.x; i < end; i += 256)
        atomicAdd(&h[dst[i] >> 7], 1);
    __syncthreads();
    for (int i = threadIdx.x; i < NBUCK; i += 256)
        if (h[i]) atomicAdd(&bcnt[i], h[i]);
}

// Single-block exclusive scan over NBUCK counts -> boff & gcur.
__global__ void k_scanN(const int* __restrict__ bcnt, int* __restrict__ boff,
                        int* __restrict__ gcur) {
    __shared__ int tmp[256];
    int tid = threadIdx.x;
    int carry = 0;
    for (int c = 0; c < (NBUCK + 255) / 256; c++) {
        int i = c * 256 + tid;
        int v = (i < NBUCK) ? bcnt[i] : 0;
        tmp[tid] = v;
        __syncthreads();
        int run = v;
        for (int off = 1; off < 256; off <<= 1) {
            int t = (tid >= off) ? tmp[tid - off] : 0;
            __syncthreads();
            run += t;
            tmp[tid] = run;
            __syncthreads();
        }
        int excl = carry + run - v;
        if (i < NBUCK) { boff[i] = excl; gcur[i] = excl; }
        int tot = tmp[255];
        __syncthreads();
        carry += tot;
    }
    if (tid == 0) boff[NBUCK] = N_EDGES;
}

// ---------------- stage 1: bucket scatter (bulk reservation, dense runs) ----------------
// Payload: (src<<7 | dst&127, weight) = 8B.
__global__ __launch_bounds__(256) void k_scat1(const int* __restrict__ src,
                                               const int* __restrict__ dst,
                                               const float* __restrict__ ew,
                                               int* __restrict__ gcur,
                                               int2* __restrict__ ebuf) {
    __shared__ int h[NBUCK];
    __shared__ int rb[NBUCK];
    for (int i = threadIdx.x; i < NBUCK; i += 256) h[i] = 0;
    __syncthreads();
    int base = blockIdx.x * EPW;
    int end  = min(base + EPW, N_EDGES);
    for (int i = base + threadIdx.x; i < end; i += 256)
        atomicAdd(&h[dst[i] >> 7], 1);
    __syncthreads();
    for (int i = threadIdx.x; i < NBUCK; i += 256) {
        int c = h[i];
        if (c) rb[i] = atomicAdd(&gcur[i], c);   // reserve contiguous range
    }
    __syncthreads();
    for (int i = base + threadIdx.x; i < end; i += 256) {
        int d  = dst[i];
        int bk = d >> 7;
        int p  = atomicAdd(&rb[bk], 1);          // LDS int cursor (native, fast)
        ebuf[p] = make_int2((src[i] << 7) | (d & 127), __float_as_int(ew[i]));
    }
}

// ---------------- stage 2: per-bucket counting sort (in-place via LDS) + rowptr ----------------
__global__ __launch_bounds__(512) void k_sortb(int2* __restrict__ ebuf,
                                               const int* __restrict__ boff,
                                               int* __restrict__ rowptr) {
    __shared__ int2 se[CAP];
    __shared__ int cnt[BSZ];
    __shared__ int cur[BSZ];
    int tid = threadIdx.x;
    int b   = blockIdx.x;
    int e0 = boff[b], e1 = boff[b + 1];
    int m  = e1 - e0;
    if (tid < BSZ) cnt[tid] = 0;
    __syncthreads();
    int2 ovf;
    bool hasOvf = false;
    for (int i = tid; i < m; i += 512) {          // all GLOBAL reads happen here
        int2 v = ebuf[e0 + i];
        if (i < CAP) se[i] = v;
        else { ovf = v; hasOvf = true; }          // statistically never (m~2048±45)
        atomicAdd(&cnt[v.x & (BSZ - 1)], 1);
    }
    __syncthreads();
    if (tid < 64) {                               // wave-0 shfl scan of 128 counts
        int a  = cnt[tid * 2], bq = cnt[tid * 2 + 1];
        int s  = a + bq;
        int incl = s;
        #pragma unroll
        for (int off = 1; off < 64; off <<= 1) {
            int t = __shfl_up(incl, off, 64);
            if (tid >= off) incl += t;
        }
        int ex = incl - s;                        // exclusive prefix of this pair
        cur[tid * 2]     = ex;
        cur[tid * 2 + 1] = ex + a;
        int node = b * BSZ + tid * 2;
        if (node     <= N_NODES) rowptr[node]     = e0 + ex;
        if (node + 1 <= N_NODES) rowptr[node + 1] = e0 + ex + a;
    }
    __syncthreads();
    for (int i = tid; i < m && i < CAP; i += 512) {
        int2 v = se[i];
        int p = atomicAdd(&cur[v.x & (BSZ - 1)], 1);
        ebuf[e0 + p] = v;
    }
    if (hasOvf) {
        int p = atomicAdd(&cur[ovf.x & (BSZ - 1)], 1);
        ebuf[e0 + p] = ovf;
    }
}

// ---------------- GEMM: H[n x 128](fp16) = X[n x 128] @ W[128 x 128] ----------------
template<bool XF16>
__global__ __launch_bounds__(256) void k_gemm(const void* __restrict__ Xv,
                                              const float* __restrict__ W,
                                              _Float16* __restrict__ H, int n) {
    __shared__ float sW[128][64];   // sW[k][c]
    __shared__ float sX[128][64];   // sX[k][r]
    int rows0 = blockIdx.x * 64;
    int cols0 = blockIdx.y * 64;
    int tid = threadIdx.x;

    for (int i = 0; i < 8; i++) {
        int L4 = i * 256 + tid;
        int k  = L4 >> 4;
        int c4 = L4 & 15;
        float4 w4 = *(const float4*)&W[k * 128 + cols0 + c4 * 4];
        *(float4*)&sW[k][c4 * 4] = w4;
    }
    {
        int r  = tid >> 2;
        int kq = (tid & 3) * 32;
        int rg = rows0 + r;
        if (XF16) {
            const _Float16* Xh = (const _Float16*)Xv + (size_t)rg * 128;
            for (int j = 0; j < 4; j++) {
                half8n v = half8n(0);
                if (rg < n) v = *(const half8n*)(Xh + kq + j * 8);
                int kk = kq + j * 8;
                #pragma unroll
                for (int q = 0; q < 8; q++) sX[kk + q][r] = (float)v[q];
            }
        } else {
            const float* Xf = (const float*)Xv + (size_t)rg * 128;
            for (int j = 0; j < 8; j++) {
                float4 xv = make_float4(0.f, 0.f, 0.f, 0.f);
                if (rg < n) xv = *(const float4*)(Xf + kq + j * 4);
                int kk = kq + j * 4;
                sX[kk + 0][r] = xv.x;
                sX[kk + 1][r] = xv.y;
                sX[kk + 2][r] = xv.z;
                sX[kk + 3][r] = xv.w;
            }
        }
    }
    __syncthreads();

    int tx = tid & 15;
    int ty = tid >> 4;
    float acc[4][4] = {};
    #pragma unroll 8
    for (int k = 0; k < 128; k++) {
        float4 a = *(const float4*)&sX[k][ty * 4];
        float4 b = *(const float4*)&sW[k][tx * 4];
        acc[0][0] += a.x * b.x; acc[0][1] += a.x * b.y; acc[0][2] += a.x * b.z; acc[0][3] += a.x * b.w;
        acc[1][0] += a.y * b.x; acc[1][1] += a.y * b.y; acc[1][2] += a.y * b.z; acc[1][3] += a.y * b.w;
        acc[2][0] += a.z * b.x; acc[2][1] += a.z * b.y; acc[2][2] += a.z * b.z; acc[2][3] += a.z * b.w;
        acc[3][0] += a.w * b.x; acc[3][1] += a.w * b.y; acc[3][2] += a.w * b.z; acc[3][3] += a.w * b.w;
    }
    for (int i = 0; i < 4; i++) {
        int row = rows0 + ty * 4 + i;
        if (row < n) {
            half4n o;
            o[0] = (_Float16)acc[i][0]; o[1] = (_Float16)acc[i][1];
            o[2] = (_Float16)acc[i][2]; o[3] = (_Float16)acc[i][3];
            *(half4n*)&H[(size_t)row * 128 + cols0 + tx * 4] = o;
        }
    }
}

// ---------------- Aggregation: out[n] = tanh(sum_e w_e * H[src_e]) ----------------
// One wave per node. 16 lanes cover the 256B fp16 row (16B/lane);
// 4 lane-groups process 4 edges concurrently; shfl_xor(16/32) combines.
template<bool OUTF16>
__global__ __launch_bounds__(256) void k_agg(const _Float16* __restrict__ H,
                                             const int* __restrict__ rowptr,
                                             const int2* __restrict__ ebuf,
                                             void* __restrict__ outv, int n) {
    int wid  = (blockIdx.x * 256 + threadIdx.x) >> 6;
    int lane = threadIdx.x & 63;
    if (wid >= n) return;
    int g = lane >> 4;        // edge slot 0..3
    int c = lane & 15;        // columns c*8 .. c*8+7
    int e0 = rowptr[wid], e1 = rowptr[wid + 1];
    float acc[8] = {};
    #pragma unroll 2
    for (int eb = e0; eb < e1; eb += 4) {
        int e  = eb + g;
        int ec = (e < e1) ? e : (e1 - 1);        // clamp (branchless; e1>e0 here)
        int2 ed = ebuf[ec];
        float w = (e < e1) ? __int_as_float(ed.y) : 0.f;
        half8n v = *(const half8n*)(H + (size_t)(ed.x >> 7) * 128 + c * 8);
        #pragma unroll
        for (int j = 0; j < 8; j++) acc[j] += w * (float)v[j];
    }
    float t[8];
    #pragma unroll
    for (int j = 0; j < 8; j++) {
        float a = acc[j];
        a += __shfl_xor(a, 16, 64);
        a += __shfl_xor(a, 32, 64);
        t[j] = tanhf(a);
    }
    if (OUTF16) {
        if (g == 0) {
            half8n hv;
            #pragma unroll
            for (int j = 0; j < 8; j++) hv[j] = (_Float16)t[j];
            uint4n o = *(uint4n*)&hv;
            __builtin_nontemporal_store(o, (uint4n*)((_Float16*)outv + (size_t)wid * 128 + c * 8));
        }
    } else {
        if (g < 2) {
            float4n o;
            o.x = t[g * 4 + 0]; o.y = t[g * 4 + 1];
            o.z = t[g * 4 + 2]; o.w = t[g * 4 + 3];
            __builtin_nontemporal_store(o, (float4n*)((float*)outv + (size_t)wid * 128 + c * 8 + g * 4));
        }
    }
}

// ---------------- launch ----------------

extern "C" void kernel_launch(void* const* d_in, const int* in_sizes, int n_in,
                              void* d_out, int out_size, void* d_ws, size_t ws_size,
                              hipStream_t stream) {
    const float* x    = (const float*)d_in[0];
    const int*   esrc = (const int*)d_in[1];
    const int*   edst = (const int*)d_in[2];
    const float* ew   = (const float*)d_in[3];
    const float* W1   = (const float*)d_in[4];
    const float* W2   = (const float*)d_in[5];
    float* out = (float*)d_out;

    // Workspace layout (~64.5 MB):
    _Float16* hbuf = (_Float16*)d_ws;                      // N*D fp16 (25.6 MB)
    _Float16* act1 = hbuf + (size_t)N_NODES * D;           // N*D fp16 (25.6 MB)
    int2* ebuf     = (int2*)(act1 + (size_t)N_NODES * D);  // E int2 (12.8 MB), 8B-aligned
    int*  bcnt     = (int*)(ebuf + N_EDGES);               // NBUCK
    int*  boff     = bcnt + NBUCK;                         // NBUCK+1
    int*  gcur     = boff + (NBUCK + 1);                   // NBUCK
    int*  rowptr   = gcur + NBUCK;                         // N+1 ints (0.4 MB)
    (void)ws_size; (void)in_sizes; (void)n_in; (void)out_size;

    // --- CSR build (graph identical for both layers) ---
    k_zero <<<(NBUCK + 255) / 256, 256, 0, stream>>>(bcnt, NBUCK);
    k_hist1<<<NWG1, 256, 0, stream>>>(edst, bcnt);
    k_scanN<<<1, 256, 0, stream>>>(bcnt, boff, gcur);
    k_scat1<<<NWG1, 256, 0, stream>>>(esrc, edst, ew, gcur, ebuf);
    k_sortb<<<NBUCK, 512, 0, stream>>>(ebuf, boff, rowptr);

    dim3 gg((N_NODES + 63) / 64, 2);
    int agg_blocks = (N_NODES * 64 + 255) / 256;  // one wave per node

    // --- layer 1 ---
    k_gemm<false><<<gg, 256, 0, stream>>>(x, W1, hbuf, N_NODES);
    k_agg<true><<<agg_blocks, 256, 0, stream>>>(hbuf, rowptr, ebuf, act1, N_NODES);
    // --- layer 2 ---
    k_gemm<true><<<gg, 256, 0, stream>>>(act1, W2, hbuf, N_NODES);
    k_agg<false><<<agg_blocks, 256, 0, stream>>>(hbuf, rowptr, ebuf, out, N_NODES);
}

// Round 7
// 298.682 us; speedup vs baseline: 9.8649x; 1.0710x over previous
//
#include <hip/hip_runtime.h>
#include <hip/hip_bf16.h>

#define N_NODES 100000
#define N_EDGES 1600000
#define D 128
#define BSZ 128                         // dst nodes per bucket
#define NBUCK 782                       // ceil(N_NODES / BSZ)
#define EPW 8192                        // edges per WG in hist/scatter
#define NWG1 ((N_EDGES + EPW - 1) / EPW)  // 196
#define CAP 4096                        // LDS edge staging per bucket (mean 2048)

typedef unsigned int  uint4n  __attribute__((ext_vector_type(4)));
typedef float         float4n __attribute__((ext_vector_type(4)));
typedef _Float16      half8n  __attribute__((ext_vector_type(8)));
typedef _Float16      half4n  __attribute__((ext_vector_type(4)));

// tanh(x) = 1 - 2/(exp2(2*log2e*x)+1); hw exp2+rcp, abs err ~2e-7.
__device__ __forceinline__ float fast_tanh(float x) {
    float t = __builtin_amdgcn_exp2f(x * 2.885390081777927f);
    return 1.0f - 2.0f * __builtin_amdgcn_rcpf(t + 1.0f);
}

// ---------------- stage 0: bucket histogram (LDS-staged, low contention) ----------------

__global__ void k_zero(int* __restrict__ p, int n) {
    int i = blockIdx.x * 256 + threadIdx.x;
    if (i < n) p[i] = 0;
}

__global__ __launch_bounds__(256) void k_hist1(const int* __restrict__ dst,
                                               int* __restrict__ bcnt) {
    __shared__ int h[NBUCK];
    for (int i = threadIdx.x; i < NBUCK; i += 256) h[i] = 0;
    __syncthreads();
    int base = blockIdx.x * EPW;
    int end  = min(base + EPW, N_EDGES);
    for (int i = base + threadIdx.x; i < end; i += 256)
        atomicAdd(&h[dst[i] >> 7], 1);
    __syncthreads();
    for (int i = threadIdx.x; i < NBUCK; i += 256)
        if (h[i]) atomicAdd(&bcnt[i], h[i]);
}

// Single-block exclusive scan over NBUCK counts -> boff & gcur.
__global__ void k_scanN(const int* __restrict__ bcnt, int* __restrict__ boff,
                        int* __restrict__ gcur) {
    __shared__ int tmp[256];
    int tid = threadIdx.x;
    int carry = 0;
    for (int c = 0; c < (NBUCK + 255) / 256; c++) {
        int i = c * 256 + tid;
        int v = (i < NBUCK) ? bcnt[i] : 0;
        tmp[tid] = v;
        __syncthreads();
        int run = v;
        for (int off = 1; off < 256; off <<= 1) {
            int t = (tid >= off) ? tmp[tid - off] : 0;
            __syncthreads();
            run += t;
            tmp[tid] = run;
            __syncthreads();
        }
        int excl = carry + run - v;
        if (i < NBUCK) { boff[i] = excl; gcur[i] = excl; }
        int tot = tmp[255];
        __syncthreads();
        carry += tot;
    }
    if (tid == 0) boff[NBUCK] = N_EDGES;
}

// ---------------- stage 1: bucket scatter (bulk reservation, dense runs) ----------------
// Payload: (src<<7 | dst&127, weight) = 8B.
__global__ __launch_bounds__(256) void k_scat1(const int* __restrict__ src,
                                               const int* __restrict__ dst,
                                               const float* __restrict__ ew,
                                               int* __restrict__ gcur,
                                               int2* __restrict__ ebuf) {
    __shared__ int h[NBUCK];
    __shared__ int rb[NBUCK];
    for (int i = threadIdx.x; i < NBUCK; i += 256) h[i] = 0;
    __syncthreads();
    int base = blockIdx.x * EPW;
    int end  = min(base + EPW, N_EDGES);
    for (int i = base + threadIdx.x; i < end; i += 256)
        atomicAdd(&h[dst[i] >> 7], 1);
    __syncthreads();
    for (int i = threadIdx.x; i < NBUCK; i += 256) {
        int c = h[i];
        if (c) rb[i] = atomicAdd(&gcur[i], c);   // reserve contiguous range
    }
    __syncthreads();
    for (int i = base + threadIdx.x; i < end; i += 256) {
        int d  = dst[i];
        int bk = d >> 7;
        int p  = atomicAdd(&rb[bk], 1);          // LDS int cursor (native, fast)
        ebuf[p] = make_int2((src[i] << 7) | (d & 127), __float_as_int(ew[i]));
    }
}

// ---------------- stage 2: per-bucket counting sort (in-place via LDS) + rowptr ----------------
__global__ __launch_bounds__(512) void k_sortb(int2* __restrict__ ebuf,
                                               const int* __restrict__ boff,
                                               int* __restrict__ rowptr) {
    __shared__ int2 se[CAP];
    __shared__ int cnt[BSZ];
    __shared__ int cur[BSZ];
    int tid = threadIdx.x;
    int b   = blockIdx.x;
    int e0 = boff[b], e1 = boff[b + 1];
    int m  = e1 - e0;
    if (tid < BSZ) cnt[tid] = 0;
    __syncthreads();
    int2 ovf;
    bool hasOvf = false;
    for (int i = tid; i < m; i += 512) {          // all GLOBAL reads happen here
        int2 v = ebuf[e0 + i];
        if (i < CAP) se[i] = v;
        else { ovf = v; hasOvf = true; }          // statistically never (m~2048±45)
        atomicAdd(&cnt[v.x & (BSZ - 1)], 1);
    }
    __syncthreads();
    if (tid < 64) {                               // wave-0 shfl scan of 128 counts
        int a  = cnt[tid * 2], bq = cnt[tid * 2 + 1];
        int s  = a + bq;
        int incl = s;
        #pragma unroll
        for (int off = 1; off < 64; off <<= 1) {
            int t = __shfl_up(incl, off, 64);
            if (tid >= off) incl += t;
        }
        int ex = incl - s;                        // exclusive prefix of this pair
        cur[tid * 2]     = ex;
        cur[tid * 2 + 1] = ex + a;
        int node = b * BSZ + tid * 2;
        if (node     <= N_NODES) rowptr[node]     = e0 + ex;
        if (node + 1 <= N_NODES) rowptr[node + 1] = e0 + ex + a;
    }
    __syncthreads();
    for (int i = tid; i < m && i < CAP; i += 512) {
        int2 v = se[i];
        int p = atomicAdd(&cur[v.x & (BSZ - 1)], 1);
        ebuf[e0 + p] = v;
    }
    if (hasOvf) {
        int p = atomicAdd(&cur[ovf.x & (BSZ - 1)], 1);
        ebuf[e0 + p] = ovf;
    }
}

// ---------------- GEMM: H[n x 128](fp16) = X[n x 128] @ W[128 x 128] ----------------
template<bool XF16>
__global__ __launch_bounds__(256) void k_gemm(const void* __restrict__ Xv,
                                              const float* __restrict__ W,
                                              _Float16* __restrict__ H, int n) {
    __shared__ float sW[128][64];   // sW[k][c]
    __shared__ float sX[128][64];   // sX[k][r]
    int rows0 = blockIdx.x * 64;
    int cols0 = blockIdx.y * 64;
    int tid = threadIdx.x;

    for (int i = 0; i < 8; i++) {
        int L4 = i * 256 + tid;
        int k  = L4 >> 4;
        int c4 = L4 & 15;
        float4 w4 = *(const float4*)&W[k * 128 + cols0 + c4 * 4];
        *(float4*)&sW[k][c4 * 4] = w4;
    }
    {
        int r  = tid >> 2;
        int kq = (tid & 3) * 32;
        int rg = rows0 + r;
        if (XF16) {
            const _Float16* Xh = (const _Float16*)Xv + (size_t)rg * 128;
            for (int j = 0; j < 4; j++) {
                half8n v = half8n(0);
                if (rg < n) v = *(const half8n*)(Xh + kq + j * 8);
                int kk = kq + j * 8;
                #pragma unroll
                for (int q = 0; q < 8; q++) sX[kk + q][r] = (float)v[q];
            }
        } else {
            const float* Xf = (const float*)Xv + (size_t)rg * 128;
            for (int j = 0; j < 8; j++) {
                float4 xv = make_float4(0.f, 0.f, 0.f, 0.f);
                if (rg < n) xv = *(const float4*)(Xf + kq + j * 4);
                int kk = kq + j * 4;
                sX[kk + 0][r] = xv.x;
                sX[kk + 1][r] = xv.y;
                sX[kk + 2][r] = xv.z;
                sX[kk + 3][r] = xv.w;
            }
        }
    }
    __syncthreads();

    int tx = tid & 15;
    int ty = tid >> 4;
    float acc[4][4] = {};
    #pragma unroll 8
    for (int k = 0; k < 128; k++) {
        float4 a = *(const float4*)&sX[k][ty * 4];
        float4 b = *(const float4*)&sW[k][tx * 4];
        acc[0][0] += a.x * b.x; acc[0][1] += a.x * b.y; acc[0][2] += a.x * b.z; acc[0][3] += a.x * b.w;
        acc[1][0] += a.y * b.x; acc[1][1] += a.y * b.y; acc[1][2] += a.y * b.z; acc[1][3] += a.y * b.w;
        acc[2][0] += a.z * b.x; acc[2][1] += a.z * b.y; acc[2][2] += a.z * b.z; acc[2][3] += a.z * b.w;
        acc[3][0] += a.w * b.x; acc[3][1] += a.w * b.y; acc[3][2] += a.w * b.z; acc[3][3] += a.w * b.w;
    }
    for (int i = 0; i < 4; i++) {
        int row = rows0 + ty * 4 + i;
        if (row < n) {
            half4n o;
            o[0] = (_Float16)acc[i][0]; o[1] = (_Float16)acc[i][1];
            o[2] = (_Float16)acc[i][2]; o[3] = (_Float16)acc[i][3];
            *(half4n*)&H[(size_t)row * 128 + cols0 + tx * 4] = o;
        }
    }
}

// ---------------- Aggregation: out[n] = tanh(sum_e w_e * H[src_e]) ----------------
// One wave per node. 16 lanes cover the 256B fp16 row (16B/lane);
// 4 lane-groups process 4 edges concurrently; shfl_xor(16/32) combines.
// Inner loop: v_fma_mix (fused f16->f32 cvt + f32 FMA) via __builtin_fmaf pattern.
template<bool OUTF16>
__global__ __launch_bounds__(256) void k_agg(const _Float16* __restrict__ H,
                                             const int* __restrict__ rowptr,
                                             const int2* __restrict__ ebuf,
                                             void* __restrict__ outv, int n) {
    int wid  = (blockIdx.x * 256 + threadIdx.x) >> 6;
    int lane = threadIdx.x & 63;
    if (wid >= n) return;
    int g = lane >> 4;        // edge slot 0..3
    int c = lane & 15;        // columns c*8 .. c*8+7
    const char* Hc = (const char*)H + (c << 4);   // per-lane column base (16B)
    int e0 = rowptr[wid], e1 = rowptr[wid + 1];
    float acc[8] = {};
    #pragma unroll 2
    for (int eb = e0; eb < e1; eb += 4) {
        int e  = eb + g;
        int ec = (e < e1) ? e : (e1 - 1);        // clamp (branchless; e1>e0 here)
        int2 ed = ebuf[ec];
        float w = (e < e1) ? __int_as_float(ed.y) : 0.f;
        // byte offset of row = src*256 = (ed.x & ~127) << 1
        half8n v = *(const half8n*)(Hc + ((size_t)((unsigned)ed.x & 0xFFFFFF80u) << 1));
        #pragma unroll
        for (int j = 0; j < 8; j++) acc[j] = __builtin_fmaf((float)v[j], w, acc[j]);
    }
    float t[8];
    #pragma unroll
    for (int j = 0; j < 8; j++) {
        float a = acc[j];
        a += __shfl_xor(a, 16, 64);
        a += __shfl_xor(a, 32, 64);
        t[j] = fast_tanh(a);
    }
    if (OUTF16) {
        if (g == 0) {
            half8n hv;
            #pragma unroll
            for (int j = 0; j < 8; j++) hv[j] = (_Float16)t[j];
            uint4n o = *(uint4n*)&hv;
            __builtin_nontemporal_store(o, (uint4n*)((_Float16*)outv + (size_t)wid * 128 + c * 8));
        }
    } else {
        if (g < 2) {
            float4n o;
            o.x = t[g * 4 + 0]; o.y = t[g * 4 + 1];
            o.z = t[g * 4 + 2]; o.w = t[g * 4 + 3];
            __builtin_nontemporal_store(o, (float4n*)((float*)outv + (size_t)wid * 128 + c * 8 + g * 4));
        }
    }
}

// ---------------- launch ----------------

extern "C" void kernel_launch(void* const* d_in, const int* in_sizes, int n_in,
                              void* d_out, int out_size, void* d_ws, size_t ws_size,
                              hipStream_t stream) {
    const float* x    = (const float*)d_in[0];
    const int*   esrc = (const int*)d_in[1];
    const int*   edst = (const int*)d_in[2];
    const float* ew   = (const float*)d_in[3];
    const float* W1   = (const float*)d_in[4];
    const float* W2   = (const float*)d_in[5];
    float* out = (float*)d_out;

    // Workspace layout (~64.5 MB):
    _Float16* hbuf = (_Float16*)d_ws;                      // N*D fp16 (25.6 MB)
    _Float16* act1 = hbuf + (size_t)N_NODES * D;           // N*D fp16 (25.6 MB)
    int2* ebuf     = (int2*)(act1 + (size_t)N_NODES * D);  // E int2 (12.8 MB), 8B-aligned
    int*  bcnt     = (int*)(ebuf + N_EDGES);               // NBUCK
    int*  boff     = bcnt + NBUCK;                         // NBUCK+1
    int*  gcur     = boff + (NBUCK + 1);                   // NBUCK
    int*  rowptr   = gcur + NBUCK;                         // N+1 ints (0.4 MB)
    (void)ws_size; (void)in_sizes; (void)n_in; (void)out_size;

    // --- CSR build (graph identical for both layers) ---
    k_zero <<<(NBUCK + 255) / 256, 256, 0, stream>>>(bcnt, NBUCK);
    k_hist1<<<NWG1, 256, 0, stream>>>(edst, bcnt);
    k_scanN<<<1, 256, 0, stream>>>(bcnt, boff, gcur);
    k_scat1<<<NWG1, 256, 0, stream>>>(esrc, edst, ew, gcur, ebuf);
    k_sortb<<<NBUCK, 512, 0, stream>>>(ebuf, boff, rowptr);

    dim3 gg((N_NODES + 63) / 64, 2);
    int agg_blocks = (N_NODES * 64 + 255) / 256;  // one wave per node

    // --- layer 1 ---
    k_gemm<false><<<gg, 256, 0, stream>>>(x, W1, hbuf, N_NODES);
    k_agg<true><<<agg_blocks, 256, 0, stream>>>(hbuf, rowptr, ebuf, act1, N_NODES);
    // --- layer 2 ---
    k_gemm<true><<<gg, 256, 0, stream>>>(act1, W2, hbuf, N_NODES);
    k_agg<false><<<agg_blocks, 256, 0, stream>>>(hbuf, rowptr, ebuf, out, N_NODES);
}

// Round 8
// 254.720 us; speedup vs baseline: 11.5674x; 1.1726x over previous
//
#include <hip/hip_runtime.h>
#include <hip/hip_bf16.h>

#define N_NODES 100000
#define N_EDGES 1600000
#define D 128
#define BSZ 128                         // dst nodes per bucket
#define NBUCK 782                       // ceil(N_NODES / BSZ)
#define EPW 8192                        // edges per WG in hist/scatter
#define NWG1 ((N_EDGES + EPW - 1) / EPW)  // 196
#define CAP 4096                        // LDS edge staging per bucket (mean 2048)

typedef unsigned int  uint4n  __attribute__((ext_vector_type(4)));
typedef float         float4n __attribute__((ext_vector_type(4)));
typedef _Float16      half8n  __attribute__((ext_vector_type(8)));
typedef _Float16      half4n  __attribute__((ext_vector_type(4)));

// swizzled LDS byte offset for element (row, kb): 256B per row, XOR bits 4-7
#define SWZ(row, kb) (((row) << 8) + ((kb) ^ (((row) & 15) << 4)))

// tanh(x) = 1 - 2/(exp2(2*log2e*x)+1); hw exp2+rcp, abs err ~2e-7.
__device__ __forceinline__ float fast_tanh(float x) {
    float t = __builtin_amdgcn_exp2f(x * 2.885390081777927f);
    return 1.0f - 2.0f * __builtin_amdgcn_rcpf(t + 1.0f);
}

// ---------------- stage 0: bucket histogram (LDS-staged, low contention) ----------------

__global__ void k_zero(int* __restrict__ p, int n) {
    int i = blockIdx.x * 256 + threadIdx.x;
    if (i < n) p[i] = 0;
}

__global__ __launch_bounds__(256) void k_hist1(const int* __restrict__ dst,
                                               int* __restrict__ bcnt) {
    __shared__ int h[NBUCK];
    for (int i = threadIdx.x; i < NBUCK; i += 256) h[i] = 0;
    __syncthreads();
    int base = blockIdx.x * EPW;
    int end  = min(base + EPW, N_EDGES);
    for (int i = base + threadIdx.x; i < end; i += 256)
        atomicAdd(&h[dst[i] >> 7], 1);
    __syncthreads();
    for (int i = threadIdx.x; i < NBUCK; i += 256)
        if (h[i]) atomicAdd(&bcnt[i], h[i]);
}

// Single-block exclusive scan over NBUCK counts -> boff & gcur.
__global__ void k_scanN(const int* __restrict__ bcnt, int* __restrict__ boff,
                        int* __restrict__ gcur) {
    __shared__ int tmp[256];
    int tid = threadIdx.x;
    int carry = 0;
    for (int c = 0; c < (NBUCK + 255) / 256; c++) {
        int i = c * 256 + tid;
        int v = (i < NBUCK) ? bcnt[i] : 0;
        tmp[tid] = v;
        __syncthreads();
        int run = v;
        for (int off = 1; off < 256; off <<= 1) {
            int t = (tid >= off) ? tmp[tid - off] : 0;
            __syncthreads();
            run += t;
            tmp[tid] = run;
            __syncthreads();
        }
        int excl = carry + run - v;
        if (i < NBUCK) { boff[i] = excl; gcur[i] = excl; }
        int tot = tmp[255];
        __syncthreads();
        carry += tot;
    }
    if (tid == 0) boff[NBUCK] = N_EDGES;
}

// ---------------- stage 1: bucket scatter (bulk reservation, dense runs) ----------------
// Payload: (src<<7 | dst&127, weight) = 8B.
__global__ __launch_bounds__(256) void k_scat1(const int* __restrict__ src,
                                               const int* __restrict__ dst,
                                               const float* __restrict__ ew,
                                               int* __restrict__ gcur,
                                               int2* __restrict__ ebuf) {
    __shared__ int h[NBUCK];
    __shared__ int rb[NBUCK];
    for (int i = threadIdx.x; i < NBUCK; i += 256) h[i] = 0;
    __syncthreads();
    int base = blockIdx.x * EPW;
    int end  = min(base + EPW, N_EDGES);
    for (int i = base + threadIdx.x; i < end; i += 256)
        atomicAdd(&h[dst[i] >> 7], 1);
    __syncthreads();
    for (int i = threadIdx.x; i < NBUCK; i += 256) {
        int c = h[i];
        if (c) rb[i] = atomicAdd(&gcur[i], c);   // reserve contiguous range
    }
    __syncthreads();
    for (int i = base + threadIdx.x; i < end; i += 256) {
        int d  = dst[i];
        int bk = d >> 7;
        int p  = atomicAdd(&rb[bk], 1);          // LDS int cursor (native, fast)
        ebuf[p] = make_int2((src[i] << 7) | (d & 127), __float_as_int(ew[i]));
    }
}

// ---------------- stage 2: per-bucket counting sort (in-place via LDS) + rowptr ----------------
__global__ __launch_bounds__(512) void k_sortb(int2* __restrict__ ebuf,
                                               const int* __restrict__ boff,
                                               int* __restrict__ rowptr) {
    __shared__ int2 se[CAP];
    __shared__ int cnt[BSZ];
    __shared__ int cur[BSZ];
    int tid = threadIdx.x;
    int b   = blockIdx.x;
    int e0 = boff[b], e1 = boff[b + 1];
    int m  = e1 - e0;
    if (tid < BSZ) cnt[tid] = 0;
    __syncthreads();
    int2 ovf;
    bool hasOvf = false;
    for (int i = tid; i < m; i += 512) {          // all GLOBAL reads happen here
        int2 v = ebuf[e0 + i];
        if (i < CAP) se[i] = v;
        else { ovf = v; hasOvf = true; }          // statistically never (m~2048±45)
        atomicAdd(&cnt[v.x & (BSZ - 1)], 1);
    }
    __syncthreads();
    if (tid < 64) {                               // wave-0 shfl scan of 128 counts
        int a  = cnt[tid * 2], bq = cnt[tid * 2 + 1];
        int s  = a + bq;
        int incl = s;
        #pragma unroll
        for (int off = 1; off < 64; off <<= 1) {
            int t = __shfl_up(incl, off, 64);
            if (tid >= off) incl += t;
        }
        int ex = incl - s;                        // exclusive prefix of this pair
        cur[tid * 2]     = ex;
        cur[tid * 2 + 1] = ex + a;
        int node = b * BSZ + tid * 2;
        if (node     <= N_NODES) rowptr[node]     = e0 + ex;
        if (node + 1 <= N_NODES) rowptr[node + 1] = e0 + ex + a;
    }
    __syncthreads();
    for (int i = tid; i < m && i < CAP; i += 512) {
        int2 v = se[i];
        int p = atomicAdd(&cur[v.x & (BSZ - 1)], 1);
        ebuf[e0 + p] = v;
    }
    if (hasOvf) {
        int p = atomicAdd(&cur[ovf.x & (BSZ - 1)], 1);
        ebuf[e0 + p] = ovf;
    }
}

// ---------------- GEMM (MFMA): H[n x 128](fp16) = X[n x 128] @ W[128 x 128] ----------------
// 782 blocks x 256 thr (4 waves). Block = 128-row slab, all 128 cols.
// sW: W transposed fp16, swizzled: elem (k,c) at byte SWZ(c, 2k). Preloaded to regs.
// sA: X slab fp16, swizzled: elem (r,k) at byte SWZ(r, 2k).
// Wave (m=w>>1,n=w&1): rows m*64..+64, cols n*64..+64 = 4x4 tiles of 16x16, K-steps of 32.
// Frag layouts (CDNA): A lane l -> row l&15, k=(l>>4)*8+j ; B lane l -> col l&15, same k.
// C/D: col=lane&15, row=(lane>>4)*4+reg  [verified dtype-independent].
template<bool XF16>
__global__ __launch_bounds__(256) void k_gemm(const void* __restrict__ Xv,
                                              const float* __restrict__ W,
                                              _Float16* __restrict__ H, int n) {
    __shared__ char sW[32768];
    __shared__ char sA[32768];
    int tid  = threadIdx.x;
    int lane = tid & 63, w = tid >> 6;
    int rows0 = blockIdx.x * 128;

    // --- stage W transposed+swizzled (coalesced float4 reads, scalar fp16 writes) ---
    for (int rep = 0; rep < 16; rep++) {
        int idx = rep * 1024 + tid * 4;          // element index k*128+c
        int k = idx >> 7, c = idx & 127;
        float4 wv = *(const float4*)&W[idx];
        *(_Float16*)(sW + SWZ(c + 0, k * 2)) = (_Float16)wv.x;
        *(_Float16*)(sW + SWZ(c + 1, k * 2)) = (_Float16)wv.y;
        *(_Float16*)(sW + SWZ(c + 2, k * 2)) = (_Float16)wv.z;
        *(_Float16*)(sW + SWZ(c + 3, k * 2)) = (_Float16)wv.w;
    }
    // --- stage A slab (fp16, swizzled) ---
    if (XF16) {
        const _Float16* Xh = (const _Float16*)Xv;
        for (int rep = 0; rep < 8; rep++) {
            int ef = rep * 2048 + tid * 8;       // element index r*128+c
            int r = ef >> 7, c = ef & 127;
            int rg = rows0 + r;
            half8n v = half8n(0);
            if (rg < n) v = *(const half8n*)(Xh + (size_t)rg * 128 + c);
            *(half8n*)(sA + SWZ(r, c * 2)) = v;
        }
    } else {
        const float* Xf = (const float*)Xv;
        for (int rep = 0; rep < 16; rep++) {
            int ef = rep * 1024 + tid * 4;
            int r = ef >> 7, c = ef & 127;
            int rg = rows0 + r;
            float4 xv = make_float4(0.f, 0.f, 0.f, 0.f);
            if (rg < n) xv = *(const float4*)(Xf + (size_t)rg * 128 + c);
            half4n hv;
            hv[0] = (_Float16)xv.x; hv[1] = (_Float16)xv.y;
            hv[2] = (_Float16)xv.z; hv[3] = (_Float16)xv.w;
            *(half4n*)(sA + SWZ(r, c * 2)) = hv;
        }
    }
    __syncthreads();

    int rb = (w >> 1) * 64;      // wave row base within slab
    int cb = (w & 1) * 64;       // wave col base
    int lr = lane & 15;          // frag row/col within tile
    int kg = (lane >> 4) * 16;   // k-group byte offset ((lane>>4)*8 halves)

    // preload W frags: bw[ks][ct]
    half8n bw[4][4];
    #pragma unroll
    for (int ks = 0; ks < 4; ks++)
        #pragma unroll
        for (int ct = 0; ct < 4; ct++)
            bw[ks][ct] = *(const half8n*)(sW + SWZ(cb + ct * 16 + lr, ks * 64 + kg));

    float4n acc[4][4] = {};
    #pragma unroll
    for (int ks = 0; ks < 4; ks++) {
        half8n af[4];
        #pragma unroll
        for (int rt = 0; rt < 4; rt++)
            af[rt] = *(const half8n*)(sA + SWZ(rb + rt * 16 + lr, ks * 64 + kg));
        #pragma unroll
        for (int rt = 0; rt < 4; rt++)
            #pragma unroll
            for (int ct = 0; ct < 4; ct++)
                acc[rt][ct] = __builtin_amdgcn_mfma_f32_16x16x32_f16(af[rt], bw[ks][ct], acc[rt][ct], 0, 0, 0);
    }

    // epilogue: D col=lane&15, row=(lane>>4)*4+reg
    int rower = rows0 + rb + (lane >> 4) * 4;
    #pragma unroll
    for (int rt = 0; rt < 4; rt++) {
        #pragma unroll
        for (int ct = 0; ct < 4; ct++) {
            int col = cb + ct * 16 + lr;
            #pragma unroll
            for (int r = 0; r < 4; r++) {
                int row = rower + rt * 16 + r;
                if (row < n) H[(size_t)row * 128 + col] = (_Float16)acc[rt][ct][r];
            }
        }
    }
}

// ---------------- Aggregation: out[n] = tanh(sum_e w_e * H[src_e]) ----------------
// One wave per node. 16 lanes cover the 256B fp16 row (16B/lane);
// 4 lane-groups process 4 edges concurrently; shfl_xor(16/32) combines.
template<bool OUTF16>
__global__ __launch_bounds__(256) void k_agg(const _Float16* __restrict__ H,
                                             const int* __restrict__ rowptr,
                                             const int2* __restrict__ ebuf,
                                             void* __restrict__ outv, int n) {
    int wid  = (blockIdx.x * 256 + threadIdx.x) >> 6;
    int lane = threadIdx.x & 63;
    if (wid >= n) return;
    int g = lane >> 4;        // edge slot 0..3
    int c = lane & 15;        // columns c*8 .. c*8+7
    const char* Hc = (const char*)H + (c << 4);   // per-lane column base (16B)
    int e0 = rowptr[wid], e1 = rowptr[wid + 1];
    float acc[8] = {};
    #pragma unroll 2
    for (int eb = e0; eb < e1; eb += 4) {
        int e  = eb + g;
        int ec = (e < e1) ? e : (e1 - 1);        // clamp (branchless; e1>e0 here)
        int2 ed = ebuf[ec];
        float w = (e < e1) ? __int_as_float(ed.y) : 0.f;
        // byte offset of row = src*256 = (ed.x & ~127) << 1
        half8n v = *(const half8n*)(Hc + ((size_t)((unsigned)ed.x & 0xFFFFFF80u) << 1));
        #pragma unroll
        for (int j = 0; j < 8; j++) acc[j] = __builtin_fmaf((float)v[j], w, acc[j]);
    }
    float t[8];
    #pragma unroll
    for (int j = 0; j < 8; j++) {
        float a = acc[j];
        a += __shfl_xor(a, 16, 64);
        a += __shfl_xor(a, 32, 64);
        t[j] = fast_tanh(a);
    }
    if (OUTF16) {
        if (g == 0) {
            half8n hv;
            #pragma unroll
            for (int j = 0; j < 8; j++) hv[j] = (_Float16)t[j];
            uint4n o = *(uint4n*)&hv;
            __builtin_nontemporal_store(o, (uint4n*)((_Float16*)outv + (size_t)wid * 128 + c * 8));
        }
    } else {
        if (g < 2) {
            float4n o;
            o.x = t[g * 4 + 0]; o.y = t[g * 4 + 1];
            o.z = t[g * 4 + 2]; o.w = t[g * 4 + 3];
            __builtin_nontemporal_store(o, (float4n*)((float*)outv + (size_t)wid * 128 + c * 8 + g * 4));
        }
    }
}

// ---------------- launch ----------------

extern "C" void kernel_launch(void* const* d_in, const int* in_sizes, int n_in,
                              void* d_out, int out_size, void* d_ws, size_t ws_size,
                              hipStream_t stream) {
    const float* x    = (const float*)d_in[0];
    const int*   esrc = (const int*)d_in[1];
    const int*   edst = (const int*)d_in[2];
    const float* ew   = (const float*)d_in[3];
    const float* W1   = (const float*)d_in[4];
    const float* W2   = (const float*)d_in[5];
    float* out = (float*)d_out;

    // Workspace layout (~64.5 MB):
    _Float16* hbuf = (_Float16*)d_ws;                      // N*D fp16 (25.6 MB)
    _Float16* act1 = hbuf + (size_t)N_NODES * D;           // N*D fp16 (25.6 MB)
    int2* ebuf     = (int2*)(act1 + (size_t)N_NODES * D);  // E int2 (12.8 MB), 8B-aligned
    int*  bcnt     = (int*)(ebuf + N_EDGES);               // NBUCK
    int*  boff     = bcnt + NBUCK;                         // NBUCK+1
    int*  gcur     = boff + (NBUCK + 1);                   // NBUCK
    int*  rowptr   = gcur + NBUCK;                         // N+1 ints (0.4 MB)
    (void)ws_size; (void)in_sizes; (void)n_in; (void)out_size;

    // --- CSR build (graph identical for both layers) ---
    k_zero <<<(NBUCK + 255) / 256, 256, 0, stream>>>(bcnt, NBUCK);
    k_hist1<<<NWG1, 256, 0, stream>>>(edst, bcnt);
    k_scanN<<<1, 256, 0, stream>>>(bcnt, boff, gcur);
    k_scat1<<<NWG1, 256, 0, stream>>>(esrc, edst, ew, gcur, ebuf);
    k_sortb<<<NBUCK, 512, 0, stream>>>(ebuf, boff, rowptr);

    int gemm_blocks = (N_NODES + 127) / 128;      // 782
    int agg_blocks  = (N_NODES * 64 + 255) / 256; // one wave per node

    // --- layer 1 ---
    k_gemm<false><<<gemm_blocks, 256, 0, stream>>>(x, W1, hbuf, N_NODES);
    k_agg<true><<<agg_blocks, 256, 0, stream>>>(hbuf, rowptr, ebuf, act1, N_NODES);
    // --- layer 2 ---
    k_gemm<true><<<gemm_blocks, 256, 0, stream>>>(act1, W2, hbuf, N_NODES);
    k_agg<false><<<agg_blocks, 256, 0, stream>>>(hbuf, rowptr, ebuf, out, N_NODES);
}

// Round 9
// 242.538 us; speedup vs baseline: 12.1484x; 1.0502x over previous
//
#include <hip/hip_runtime.h>
#include <hip/hip_bf16.h>

#define N_NODES 100000
#define N_EDGES 1600000
#define D 128
#define BSZ 128                         // dst nodes per bucket
#define NBUCK 782                       // ceil(N_NODES / BSZ)
#define EPW 8192                        // edges per WG in hist/scatter
#define NWG1 ((N_EDGES + EPW - 1) / EPW)  // 196
#define CAP 4096                        // LDS edge staging per bucket (mean 2048)
#define OTS 272                         // epilogue LDS tile row stride (bytes)

typedef unsigned int  uint4n  __attribute__((ext_vector_type(4)));
typedef float         float4n __attribute__((ext_vector_type(4)));
typedef _Float16      half8n  __attribute__((ext_vector_type(8)));
typedef _Float16      half4n  __attribute__((ext_vector_type(4)));

// swizzled LDS byte offset for element (row, kb): 256B per row, XOR bits 4-7
#define SWZ(row, kb) (((row) << 8) + ((kb) ^ (((row) & 15) << 4)))

// tanh(x) = 1 - 2/(exp2(2*log2e*x)+1); hw exp2+rcp, abs err ~2e-7.
__device__ __forceinline__ float fast_tanh(float x) {
    float t = __builtin_amdgcn_exp2f(x * 2.885390081777927f);
    return 1.0f - 2.0f * __builtin_amdgcn_rcpf(t + 1.0f);
}

// ---------------- W prep: Wt = fp16(W^T) in the swizzled LDS image ----------------
// Element W[k][c] lands at byte SWZ(c, 2k) of its 32KB blob.
__global__ __launch_bounds__(256) void k_wprep(const float* __restrict__ W1,
                                               const float* __restrict__ W2,
                                               char* __restrict__ Wt) {
    const float* W = (blockIdx.x < 16) ? W1 : W2;
    char* dst = Wt + ((blockIdx.x < 16) ? 0 : 32768);
    int t = (blockIdx.x & 15) * 256 + threadIdx.x;   // 0..4095
    int idx = t * 4;
    int k = idx >> 7, c = idx & 127;
    float4 wv = *(const float4*)&W[idx];
    *(_Float16*)(dst + SWZ(c + 0, k * 2)) = (_Float16)wv.x;
    *(_Float16*)(dst + SWZ(c + 1, k * 2)) = (_Float16)wv.y;
    *(_Float16*)(dst + SWZ(c + 2, k * 2)) = (_Float16)wv.z;
    *(_Float16*)(dst + SWZ(c + 3, k * 2)) = (_Float16)wv.w;
}

// ---------------- stage 0: bucket histogram (LDS-staged, low contention) ----------------

__global__ void k_zero(int* __restrict__ p, int n) {
    int i = blockIdx.x * 256 + threadIdx.x;
    if (i < n) p[i] = 0;
}

__global__ __launch_bounds__(256) void k_hist1(const int* __restrict__ dst,
                                               int* __restrict__ bcnt) {
    __shared__ int h[NBUCK];
    for (int i = threadIdx.x; i < NBUCK; i += 256) h[i] = 0;
    __syncthreads();
    int base = blockIdx.x * EPW;
    int end  = min(base + EPW, N_EDGES);
    for (int i = base + threadIdx.x; i < end; i += 256)
        atomicAdd(&h[dst[i] >> 7], 1);
    __syncthreads();
    for (int i = threadIdx.x; i < NBUCK; i += 256)
        if (h[i]) atomicAdd(&bcnt[i], h[i]);
}

// Single-block exclusive scan over NBUCK counts -> boff & gcur.
__global__ void k_scanN(const int* __restrict__ bcnt, int* __restrict__ boff,
                        int* __restrict__ gcur) {
    __shared__ int tmp[256];
    int tid = threadIdx.x;
    int carry = 0;
    for (int c = 0; c < (NBUCK + 255) / 256; c++) {
        int i = c * 256 + tid;
        int v = (i < NBUCK) ? bcnt[i] : 0;
        tmp[tid] = v;
        __syncthreads();
        int run = v;
        for (int off = 1; off < 256; off <<= 1) {
            int t = (tid >= off) ? tmp[tid - off] : 0;
            __syncthreads();
            run += t;
            tmp[tid] = run;
            __syncthreads();
        }
        int excl = carry + run - v;
        if (i < NBUCK) { boff[i] = excl; gcur[i] = excl; }
        int tot = tmp[255];
        __syncthreads();
        carry += tot;
    }
    if (tid == 0) boff[NBUCK] = N_EDGES;
}

// ---------------- stage 1: bucket scatter (bulk reservation, dense runs) ----------------
// Payload: (src<<7 | dst&127, weight) = 8B.
__global__ __launch_bounds__(256) void k_scat1(const int* __restrict__ src,
                                               const int* __restrict__ dst,
                                               const float* __restrict__ ew,
                                               int* __restrict__ gcur,
                                               int2* __restrict__ ebuf) {
    __shared__ int h[NBUCK];
    __shared__ int rb[NBUCK];
    for (int i = threadIdx.x; i < NBUCK; i += 256) h[i] = 0;
    __syncthreads();
    int base = blockIdx.x * EPW;
    int end  = min(base + EPW, N_EDGES);
    for (int i = base + threadIdx.x; i < end; i += 256)
        atomicAdd(&h[dst[i] >> 7], 1);
    __syncthreads();
    for (int i = threadIdx.x; i < NBUCK; i += 256) {
        int c = h[i];
        if (c) rb[i] = atomicAdd(&gcur[i], c);   // reserve contiguous range
    }
    __syncthreads();
    for (int i = base + threadIdx.x; i < end; i += 256) {
        int d  = dst[i];
        int bk = d >> 7;
        int p  = atomicAdd(&rb[bk], 1);          // LDS int cursor (native, fast)
        ebuf[p] = make_int2((src[i] << 7) | (d & 127), __float_as_int(ew[i]));
    }
}

// ---------------- stage 2: per-bucket counting sort (in-place via LDS) + rowptr ----------------
__global__ __launch_bounds__(512) void k_sortb(int2* __restrict__ ebuf,
                                               const int* __restrict__ boff,
                                               int* __restrict__ rowptr) {
    __shared__ int2 se[CAP];
    __shared__ int cnt[BSZ];
    __shared__ int cur[BSZ];
    int tid = threadIdx.x;
    int b   = blockIdx.x;
    int e0 = boff[b], e1 = boff[b + 1];
    int m  = e1 - e0;
    if (tid < BSZ) cnt[tid] = 0;
    __syncthreads();
    int2 ovf;
    bool hasOvf = false;
    for (int i = tid; i < m; i += 512) {          // all GLOBAL reads happen here
        int2 v = ebuf[e0 + i];
        if (i < CAP) se[i] = v;
        else { ovf = v; hasOvf = true; }          // statistically never (m~2048±45)
        atomicAdd(&cnt[v.x & (BSZ - 1)], 1);
    }
    __syncthreads();
    if (tid < 64) {                               // wave-0 shfl scan of 128 counts
        int a  = cnt[tid * 2], bq = cnt[tid * 2 + 1];
        int s  = a + bq;
        int incl = s;
        #pragma unroll
        for (int off = 1; off < 64; off <<= 1) {
            int t = __shfl_up(incl, off, 64);
            if (tid >= off) incl += t;
        }
        int ex = incl - s;                        // exclusive prefix of this pair
        cur[tid * 2]     = ex;
        cur[tid * 2 + 1] = ex + a;
        int node = b * BSZ + tid * 2;
        if (node     <= N_NODES) rowptr[node]     = e0 + ex;
        if (node + 1 <= N_NODES) rowptr[node + 1] = e0 + ex + a;
    }
    __syncthreads();
    for (int i = tid; i < m && i < CAP; i += 512) {
        int2 v = se[i];
        int p = atomicAdd(&cur[v.x & (BSZ - 1)], 1);
        ebuf[e0 + p] = v;
    }
    if (hasOvf) {
        int p = atomicAdd(&cur[ovf.x & (BSZ - 1)], 1);
        ebuf[e0 + p] = ovf;
    }
}

// ---------------- GEMM (MFMA): H[n x 128](fp16) = X[n x 128] @ W[128 x 128] ----------------
// 782 blocks x 256 thr (4 waves). Block = 128-row slab, all 128 cols.
// sW: pre-swizzled W^T fp16 image (straight 32KB copy from Wt).
// sA: X slab fp16, swizzled: elem (r,k) at byte SWZ(r, 2k).
// Wave (m=w>>1,n=w&1): rows m*64..+64, cols n*64..+64 = 4x4 tiles of 16x16, K=4 steps.
// Epilogue: acc -> LDS tile (stride OTS) -> coalesced half8n global stores.
template<bool XF16>
__global__ __launch_bounds__(256) void k_gemm(const void* __restrict__ Xv,
                                              const char* __restrict__ Wt,
                                              _Float16* __restrict__ H, int n) {
    __shared__ char smem[65536];
    char* sW = smem;            // [0, 32768)
    char* sA = smem + 32768;    // [32768, 65536)
    int tid  = threadIdx.x;
    int lane = tid & 63, w = tid >> 6;
    int rows0 = blockIdx.x * 128;

    // --- stage W: straight copy of pre-swizzled image (16B/lane both sides) ---
    #pragma unroll
    for (int rep = 0; rep < 8; rep++) {
        int off = rep * 4096 + tid * 16;
        *(uint4n*)(sW + off) = *(const uint4n*)(Wt + off);
    }
    // --- stage A slab (fp16, swizzled) ---
    if (XF16) {
        const _Float16* Xh = (const _Float16*)Xv;
        for (int rep = 0; rep < 8; rep++) {
            int ef = rep * 2048 + tid * 8;       // element index r*128+c
            int r = ef >> 7, c = ef & 127;
            int rg = rows0 + r;
            half8n v = half8n(0);
            if (rg < n) v = *(const half8n*)(Xh + (size_t)rg * 128 + c);
            *(half8n*)(sA + SWZ(r, c * 2)) = v;
        }
    } else {
        const float* Xf = (const float*)Xv;
        for (int rep = 0; rep < 16; rep++) {
            int ef = rep * 1024 + tid * 4;
            int r = ef >> 7, c = ef & 127;
            int rg = rows0 + r;
            float4 xv = make_float4(0.f, 0.f, 0.f, 0.f);
            if (rg < n) xv = *(const float4*)(Xf + (size_t)rg * 128 + c);
            half4n hv;
            hv[0] = (_Float16)xv.x; hv[1] = (_Float16)xv.y;
            hv[2] = (_Float16)xv.z; hv[3] = (_Float16)xv.w;
            *(half4n*)(sA + SWZ(r, c * 2)) = hv;
        }
    }
    __syncthreads();

    int rb = (w >> 1) * 64;      // wave row base within slab
    int cb = (w & 1) * 64;       // wave col base
    int lr = lane & 15;          // frag row/col within tile
    int kg = (lane >> 4) * 16;   // k-group byte offset ((lane>>4)*8 halves)

    // preload W frags: bw[ks][ct]
    half8n bw[4][4];
    #pragma unroll
    for (int ks = 0; ks < 4; ks++)
        #pragma unroll
        for (int ct = 0; ct < 4; ct++)
            bw[ks][ct] = *(const half8n*)(sW + SWZ(cb + ct * 16 + lr, ks * 64 + kg));

    float4n acc[4][4] = {};
    #pragma unroll
    for (int ks = 0; ks < 4; ks++) {
        half8n af[4];
        #pragma unroll
        for (int rt = 0; rt < 4; rt++)
            af[rt] = *(const half8n*)(sA + SWZ(rb + rt * 16 + lr, ks * 64 + kg));
        #pragma unroll
        for (int rt = 0; rt < 4; rt++)
            #pragma unroll
            for (int ct = 0; ct < 4; ct++)
                acc[rt][ct] = __builtin_amdgcn_mfma_f32_16x16x32_f16(af[rt], bw[ks][ct], acc[rt][ct], 0, 0, 0);
    }

    // --- epilogue: acc -> LDS tile -> coalesced stores ---
    __syncthreads();                              // sW/sA dead, reuse as OT
    char* OT = smem;                              // 128 rows x OTS bytes (34KB)
    int rloc = rb + (lane >> 4) * 4;              // local row base
    #pragma unroll
    for (int rt = 0; rt < 4; rt++) {
        #pragma unroll
        for (int ct = 0; ct < 4; ct++) {
            int col = cb + ct * 16 + lr;
            #pragma unroll
            for (int r = 0; r < 4; r++)
                *(_Float16*)(OT + (rloc + rt * 16 + r) * OTS + col * 2) = (_Float16)acc[rt][ct][r];
        }
    }
    __syncthreads();
    #pragma unroll
    for (int rep = 0; rep < 8; rep++) {
        int ef = rep * 2048 + tid * 8;
        int r = ef >> 7, c = ef & 127;
        int rg = rows0 + r;
        if (rg < n) {
            half8n v = *(const half8n*)(OT + r * OTS + c * 2);
            *(half8n*)&H[(size_t)rg * 128 + c] = v;
        }
    }
}

// ---------------- Aggregation: out[n] = tanh(sum_e w_e * H[src_e]) ----------------
// One wave per node. 16 lanes cover the 256B fp16 row (16B/lane);
// 4 lane-groups process 4 edges concurrently; shfl_xor(16/32) combines.
// ebuf read nontemporal (streamed; keep H rows in cache instead).
template<bool OUTF16>
__global__ __launch_bounds__(256) void k_agg(const _Float16* __restrict__ H,
                                             const int* __restrict__ rowptr,
                                             const int2* __restrict__ ebuf,
                                             void* __restrict__ outv, int n) {
    int wid  = (blockIdx.x * 256 + threadIdx.x) >> 6;
    int lane = threadIdx.x & 63;
    if (wid >= n) return;
    int g = lane >> 4;        // edge slot 0..3
    int c = lane & 15;        // columns c*8 .. c*8+7
    const char* Hc = (const char*)H + (c << 4);   // per-lane column base (16B)
    int e0 = rowptr[wid], e1 = rowptr[wid + 1];
    float acc[8] = {};
    #pragma unroll 2
    for (int eb = e0; eb < e1; eb += 4) {
        int e  = eb + g;
        int ec = (e < e1) ? e : (e1 - 1);        // clamp (branchless; e1>e0 here)
        long long edl = __builtin_nontemporal_load((const long long*)(ebuf + ec));
        unsigned edx = (unsigned)edl;
        float w = (e < e1) ? __int_as_float((int)(edl >> 32)) : 0.f;
        // byte offset of row = src*256 = (edx & ~127) << 1
        half8n v = *(const half8n*)(Hc + ((size_t)(edx & 0xFFFFFF80u) << 1));
        #pragma unroll
        for (int j = 0; j < 8; j++) acc[j] = __builtin_fmaf((float)v[j], w, acc[j]);
    }
    float t[8];
    #pragma unroll
    for (int j = 0; j < 8; j++) {
        float a = acc[j];
        a += __shfl_xor(a, 16, 64);
        a += __shfl_xor(a, 32, 64);
        t[j] = fast_tanh(a);
    }
    if (OUTF16) {
        if (g == 0) {
            half8n hv;
            #pragma unroll
            for (int j = 0; j < 8; j++) hv[j] = (_Float16)t[j];
            uint4n o = *(uint4n*)&hv;
            __builtin_nontemporal_store(o, (uint4n*)((_Float16*)outv + (size_t)wid * 128 + c * 8));
        }
    } else {
        if (g < 2) {
            float4n o;
            o.x = t[g * 4 + 0]; o.y = t[g * 4 + 1];
            o.z = t[g * 4 + 2]; o.w = t[g * 4 + 3];
            __builtin_nontemporal_store(o, (float4n*)((float*)outv + (size_t)wid * 128 + c * 8 + g * 4));
        }
    }
}

// ---------------- launch ----------------

extern "C" void kernel_launch(void* const* d_in, const int* in_sizes, int n_in,
                              void* d_out, int out_size, void* d_ws, size_t ws_size,
                              hipStream_t stream) {
    const float* x    = (const float*)d_in[0];
    const int*   esrc = (const int*)d_in[1];
    const int*   edst = (const int*)d_in[2];
    const float* ew   = (const float*)d_in[3];
    const float* W1   = (const float*)d_in[4];
    const float* W2   = (const float*)d_in[5];
    float* out = (float*)d_out;

    // Workspace layout (~64.6 MB):
    _Float16* hbuf = (_Float16*)d_ws;                      // N*D fp16 (25.6 MB)
    _Float16* act1 = hbuf + (size_t)N_NODES * D;           // N*D fp16 (25.6 MB)
    int2* ebuf     = (int2*)(act1 + (size_t)N_NODES * D);  // E int2 (12.8 MB), 8B-aligned
    int*  bcnt     = (int*)(ebuf + N_EDGES);               // NBUCK
    int*  boff     = bcnt + NBUCK;                         // NBUCK+1
    int*  gcur     = boff + (NBUCK + 1);                   // NBUCK
    int*  rowptr   = gcur + NBUCK;                         // N+1 ints (0.4 MB)
    char* Wt       = (char*)(rowptr + N_NODES + 8);        // 64 KB (two 32KB blobs)
    (void)ws_size; (void)in_sizes; (void)n_in; (void)out_size;

    // --- W prep + CSR build (graph identical for both layers) ---
    k_wprep<<<32, 256, 0, stream>>>(W1, W2, Wt);
    k_zero <<<(NBUCK + 255) / 256, 256, 0, stream>>>(bcnt, NBUCK);
    k_hist1<<<NWG1, 256, 0, stream>>>(edst, bcnt);
    k_scanN<<<1, 256, 0, stream>>>(bcnt, boff, gcur);
    k_scat1<<<NWG1, 256, 0, stream>>>(esrc, edst, ew, gcur, ebuf);
    k_sortb<<<NBUCK, 512, 0, stream>>>(ebuf, boff, rowptr);

    int gemm_blocks = (N_NODES + 127) / 128;      // 782
    int agg_blocks  = (N_NODES * 64 + 255) / 256; // one wave per node

    // --- layer 1 ---
    k_gemm<false><<<gemm_blocks, 256, 0, stream>>>(x, Wt, hbuf, N_NODES);
    k_agg<true><<<agg_blocks, 256, 0, stream>>>(hbuf, rowptr, ebuf, act1, N_NODES);
    // --- layer 2 ---
    k_gemm<true><<<gemm_blocks, 256, 0, stream>>>(act1, Wt + 32768, hbuf, N_NODES);
    k_agg<false><<<agg_blocks, 256, 0, stream>>>(hbuf, rowptr, ebuf, out, N_NODES);
}

// Round 10
// 241.343 us; speedup vs baseline: 12.2086x; 1.0050x over previous
//
#include <hip/hip_runtime.h>
#include <hip/hip_bf16.h>

#define N_NODES 100000
#define N_EDGES 1600000
#define D 128
#define BSZ 128                         // dst nodes per bucket
#define NBUCK 782                       // ceil(N_NODES / BSZ)
#define EPW 8192                        // edges per WG in hist/scatter
#define NWG1 ((N_EDGES + EPW - 1) / EPW)  // 196
#define CAP 4096                        // LDS edge staging per bucket (mean 2048)
#define OTS 272                         // epilogue LDS tile row stride (bytes)

typedef unsigned int  uint4n  __attribute__((ext_vector_type(4)));
typedef float         float4n __attribute__((ext_vector_type(4)));
typedef _Float16      half8n  __attribute__((ext_vector_type(8)));
typedef _Float16      half4n  __attribute__((ext_vector_type(4)));

// swizzled LDS byte offset for element (row, kb): 256B per row, XOR bits 4-7
#define SWZ(row, kb) (((row) << 8) + ((kb) ^ (((row) & 15) << 4)))

// tanh(x) = 1 - 2/(exp2(2*log2e*x)+1); hw exp2+rcp, abs err ~2e-7.
__device__ __forceinline__ float fast_tanh(float x) {
    float t = __builtin_amdgcn_exp2f(x * 2.885390081777927f);
    return 1.0f - 2.0f * __builtin_amdgcn_rcpf(t + 1.0f);
}

// ---------------- W prep: Wt = fp16(W^T) in the swizzled image ----------------
// Element W[k][c] lands at byte SWZ(c, 2k) of its 32KB blob.
__global__ __launch_bounds__(256) void k_wprep(const float* __restrict__ W1,
                                               const float* __restrict__ W2,
                                               char* __restrict__ Wt) {
    const float* W = (blockIdx.x < 16) ? W1 : W2;
    char* dst = Wt + ((blockIdx.x < 16) ? 0 : 32768);
    int t = (blockIdx.x & 15) * 256 + threadIdx.x;   // 0..4095
    int idx = t * 4;
    int k = idx >> 7, c = idx & 127;
    float4 wv = *(const float4*)&W[idx];
    *(_Float16*)(dst + SWZ(c + 0, k * 2)) = (_Float16)wv.x;
    *(_Float16*)(dst + SWZ(c + 1, k * 2)) = (_Float16)wv.y;
    *(_Float16*)(dst + SWZ(c + 2, k * 2)) = (_Float16)wv.z;
    *(_Float16*)(dst + SWZ(c + 3, k * 2)) = (_Float16)wv.w;
}

// ---------------- stage 0: bucket histogram (LDS-staged, low contention) ----------------

__global__ void k_zero(int* __restrict__ p, int n) {
    int i = blockIdx.x * 256 + threadIdx.x;
    if (i < n) p[i] = 0;
}

__global__ __launch_bounds__(256) void k_hist1(const int* __restrict__ dst,
                                               int* __restrict__ bcnt) {
    __shared__ int h[NBUCK];
    for (int i = threadIdx.x; i < NBUCK; i += 256) h[i] = 0;
    __syncthreads();
    int base = blockIdx.x * EPW;
    int end  = min(base + EPW, N_EDGES);
    for (int i = base + threadIdx.x; i < end; i += 256)
        atomicAdd(&h[dst[i] >> 7], 1);
    __syncthreads();
    for (int i = threadIdx.x; i < NBUCK; i += 256)
        if (h[i]) atomicAdd(&bcnt[i], h[i]);
}

// Single-block exclusive scan over NBUCK counts -> boff & gcur.
__global__ void k_scanN(const int* __restrict__ bcnt, int* __restrict__ boff,
                        int* __restrict__ gcur) {
    __shared__ int tmp[256];
    int tid = threadIdx.x;
    int carry = 0;
    for (int c = 0; c < (NBUCK + 255) / 256; c++) {
        int i = c * 256 + tid;
        int v = (i < NBUCK) ? bcnt[i] : 0;
        tmp[tid] = v;
        __syncthreads();
        int run = v;
        for (int off = 1; off < 256; off <<= 1) {
            int t = (tid >= off) ? tmp[tid - off] : 0;
            __syncthreads();
            run += t;
            tmp[tid] = run;
            __syncthreads();
        }
        int excl = carry + run - v;
        if (i < NBUCK) { boff[i] = excl; gcur[i] = excl; }
        int tot = tmp[255];
        __syncthreads();
        carry += tot;
    }
    if (tid == 0) boff[NBUCK] = N_EDGES;
}

// ---------------- stage 1: bucket scatter (bulk reservation, dense runs) ----------------
// Payload: (src<<7 | dst&127, weight) = 8B.
__global__ __launch_bounds__(256) void k_scat1(const int* __restrict__ src,
                                               const int* __restrict__ dst,
                                               const float* __restrict__ ew,
                                               int* __restrict__ gcur,
                                               int2* __restrict__ ebuf) {
    __shared__ int h[NBUCK];
    __shared__ int rb[NBUCK];
    for (int i = threadIdx.x; i < NBUCK; i += 256) h[i] = 0;
    __syncthreads();
    int base = blockIdx.x * EPW;
    int end  = min(base + EPW, N_EDGES);
    for (int i = base + threadIdx.x; i < end; i += 256)
        atomicAdd(&h[dst[i] >> 7], 1);
    __syncthreads();
    for (int i = threadIdx.x; i < NBUCK; i += 256) {
        int c = h[i];
        if (c) rb[i] = atomicAdd(&gcur[i], c);   // reserve contiguous range
    }
    __syncthreads();
    for (int i = base + threadIdx.x; i < end; i += 256) {
        int d  = dst[i];
        int bk = d >> 7;
        int p  = atomicAdd(&rb[bk], 1);          // LDS int cursor (native, fast)
        ebuf[p] = make_int2((src[i] << 7) | (d & 127), __float_as_int(ew[i]));
    }
}

// ---------------- stage 2: per-bucket counting sort (in-place via LDS) + rowptr ----------------
__global__ __launch_bounds__(512) void k_sortb(int2* __restrict__ ebuf,
                                               const int* __restrict__ boff,
                                               int* __restrict__ rowptr) {
    __shared__ int2 se[CAP];
    __shared__ int cnt[BSZ];
    __shared__ int cur[BSZ];
    int tid = threadIdx.x;
    int b   = blockIdx.x;
    int e0 = boff[b], e1 = boff[b + 1];
    int m  = e1 - e0;
    if (tid < BSZ) cnt[tid] = 0;
    __syncthreads();
    int2 ovf;
    bool hasOvf = false;
    for (int i = tid; i < m; i += 512) {          // all GLOBAL reads happen here
        int2 v = ebuf[e0 + i];
        if (i < CAP) se[i] = v;
        else { ovf = v; hasOvf = true; }          // statistically never (m~2048±45)
        atomicAdd(&cnt[v.x & (BSZ - 1)], 1);
    }
    __syncthreads();
    if (tid < 64) {                               // wave-0 shfl scan of 128 counts
        int a  = cnt[tid * 2], bq = cnt[tid * 2 + 1];
        int s  = a + bq;
        int incl = s;
        #pragma unroll
        for (int off = 1; off < 64; off <<= 1) {
            int t = __shfl_up(incl, off, 64);
            if (tid >= off) incl += t;
        }
        int ex = incl - s;                        // exclusive prefix of this pair
        cur[tid * 2]     = ex;
        cur[tid * 2 + 1] = ex + a;
        int node = b * BSZ + tid * 2;
        if (node     <= N_NODES) rowptr[node]     = e0 + ex;
        if (node + 1 <= N_NODES) rowptr[node + 1] = e0 + ex + a;
    }
    __syncthreads();
    for (int i = tid; i < m && i < CAP; i += 512) {
        int2 v = se[i];
        int p = atomicAdd(&cur[v.x & (BSZ - 1)], 1);
        ebuf[e0 + p] = v;
    }
    if (hasOvf) {
        int p = atomicAdd(&cur[ovf.x & (BSZ - 1)], 1);
        ebuf[e0 + p] = ovf;
    }
}

// ---------------- GEMM (MFMA): H[n x 128](fp16) = X[n x 128] @ W[128 x 128] ----------------
// 782 blocks x 256 thr (4 waves). Block = 128-row slab, all 128 cols.
// W frags loaded DIRECTLY from global pre-swizzled Wt (L2-broadcast, no LDS).
// sA: X slab fp16, swizzled: elem (r,k) at byte SWZ(r, 2k). LDS total 40KB -> 4 blocks/CU.
// Wave (m=w>>1,n=w&1): rows m*64..+64, cols n*64..+64 = 4x4 tiles of 16x16, K=4 steps.
// Epilogue: acc -> LDS tile (stride OTS, reuses sA) -> coalesced half8n global stores.
template<bool XF16>
__global__ __launch_bounds__(256) void k_gemm(const void* __restrict__ Xv,
                                              const char* __restrict__ Wt,
                                              _Float16* __restrict__ H, int n) {
    __shared__ char smem[40960];
    char* sA = smem;            // staging: [0, 32768); epilogue tile: [0, 34816)
    int tid  = threadIdx.x;
    int lane = tid & 63, w = tid >> 6;
    int rows0 = blockIdx.x * 128;

    int rb = (w >> 1) * 64;      // wave row base within slab
    int cb = (w & 1) * 64;       // wave col base
    int lr = lane & 15;          // frag row/col within tile
    int kg = (lane >> 4) * 16;   // k-group byte offset ((lane>>4)*8 halves)

    // preload W frags from GLOBAL pre-swizzled image (same 32KB for all blocks -> L2)
    half8n bw[4][4];
    #pragma unroll
    for (int ks = 0; ks < 4; ks++)
        #pragma unroll
        for (int ct = 0; ct < 4; ct++)
            bw[ks][ct] = *(const half8n*)(Wt + SWZ(cb + ct * 16 + lr, ks * 64 + kg));

    // --- stage A slab (fp16, swizzled) ---
    if (XF16) {
        const _Float16* Xh = (const _Float16*)Xv;
        for (int rep = 0; rep < 8; rep++) {
            int ef = rep * 2048 + tid * 8;       // element index r*128+c
            int r = ef >> 7, c = ef & 127;
            int rg = rows0 + r;
            half8n v = half8n(0);
            if (rg < n) v = *(const half8n*)(Xh + (size_t)rg * 128 + c);
            *(half8n*)(sA + SWZ(r, c * 2)) = v;
        }
    } else {
        const float* Xf = (const float*)Xv;
        for (int rep = 0; rep < 16; rep++) {
            int ef = rep * 1024 + tid * 4;
            int r = ef >> 7, c = ef & 127;
            int rg = rows0 + r;
            float4 xv = make_float4(0.f, 0.f, 0.f, 0.f);
            if (rg < n) xv = *(const float4*)(Xf + (size_t)rg * 128 + c);
            half4n hv;
            hv[0] = (_Float16)xv.x; hv[1] = (_Float16)xv.y;
            hv[2] = (_Float16)xv.z; hv[3] = (_Float16)xv.w;
            *(half4n*)(sA + SWZ(r, c * 2)) = hv;
        }
    }
    __syncthreads();

    float4n acc[4][4] = {};
    #pragma unroll
    for (int ks = 0; ks < 4; ks++) {
        half8n af[4];
        #pragma unroll
        for (int rt = 0; rt < 4; rt++)
            af[rt] = *(const half8n*)(sA + SWZ(rb + rt * 16 + lr, ks * 64 + kg));
        #pragma unroll
        for (int rt = 0; rt < 4; rt++)
            #pragma unroll
            for (int ct = 0; ct < 4; ct++)
                acc[rt][ct] = __builtin_amdgcn_mfma_f32_16x16x32_f16(af[rt], bw[ks][ct], acc[rt][ct], 0, 0, 0);
    }

    // --- epilogue: acc -> LDS tile -> coalesced stores ---
    __syncthreads();                              // sA dead, reuse as OT
    char* OT = smem;                              // 128 rows x OTS bytes (34KB)
    int rloc = rb + (lane >> 4) * 4;              // local row base
    #pragma unroll
    for (int rt = 0; rt < 4; rt++) {
        #pragma unroll
        for (int ct = 0; ct < 4; ct++) {
            int col = cb + ct * 16 + lr;
            #pragma unroll
            for (int r = 0; r < 4; r++)
                *(_Float16*)(OT + (rloc + rt * 16 + r) * OTS + col * 2) = (_Float16)acc[rt][ct][r];
        }
    }
    __syncthreads();
    #pragma unroll
    for (int rep = 0; rep < 8; rep++) {
        int ef = rep * 2048 + tid * 8;
        int r = ef >> 7, c = ef & 127;
        int rg = rows0 + r;
        if (rg < n) {
            half8n v = *(const half8n*)(OT + r * OTS + c * 2);
            *(half8n*)&H[(size_t)rg * 128 + c] = v;
        }
    }
}

// ---------------- Aggregation: out[n] = tanh(sum_e w_e * H[src_e]) ----------------
// One wave per node. 16 lanes cover the 256B fp16 row (16B/lane);
// 4 lane-groups process 4 edges concurrently; shfl_xor(16/32) combines.
template<bool OUTF16>
__global__ __launch_bounds__(256) void k_agg(const _Float16* __restrict__ H,
                                             const int* __restrict__ rowptr,
                                             const int2* __restrict__ ebuf,
                                             void* __restrict__ outv, int n) {
    int wid  = (blockIdx.x * 256 + threadIdx.x) >> 6;
    int lane = threadIdx.x & 63;
    if (wid >= n) return;
    int g = lane >> 4;        // edge slot 0..3
    int c = lane & 15;        // columns c*8 .. c*8+7
    const char* Hc = (const char*)H + (c << 4);   // per-lane column base (16B)
    int e0 = rowptr[wid], e1 = rowptr[wid + 1];
    float acc[8] = {};
    #pragma unroll 2
    for (int eb = e0; eb < e1; eb += 4) {
        int e  = eb + g;
        int ec = (e < e1) ? e : (e1 - 1);        // clamp (branchless; e1>e0 here)
        int2 ed = ebuf[ec];
        float w = (e < e1) ? __int_as_float(ed.y) : 0.f;
        // byte offset of row = src*256 = (ed.x & ~127) << 1
        half8n v = *(const half8n*)(Hc + ((size_t)((unsigned)ed.x & 0xFFFFFF80u) << 1));
        #pragma unroll
        for (int j = 0; j < 8; j++) acc[j] = __builtin_fmaf((float)v[j], w, acc[j]);
    }
    float t[8];
    #pragma unroll
    for (int j = 0; j < 8; j++) {
        float a = acc[j];
        a += __shfl_xor(a, 16, 64);
        a += __shfl_xor(a, 32, 64);
        t[j] = fast_tanh(a);
    }
    if (OUTF16) {
        if (g == 0) {
            half8n hv;
            #pragma unroll
            for (int j = 0; j < 8; j++) hv[j] = (_Float16)t[j];
            uint4n o = *(uint4n*)&hv;
            __builtin_nontemporal_store(o, (uint4n*)((_Float16*)outv + (size_t)wid * 128 + c * 8));
        }
    } else {
        if (g < 2) {
            float4n o;
            o.x = t[g * 4 + 0]; o.y = t[g * 4 + 1];
            o.z = t[g * 4 + 2]; o.w = t[g * 4 + 3];
            __builtin_nontemporal_store(o, (float4n*)((float*)outv + (size_t)wid * 128 + c * 8 + g * 4));
        }
    }
}

// ---------------- launch ----------------

extern "C" void kernel_launch(void* const* d_in, const int* in_sizes, int n_in,
                              void* d_out, int out_size, void* d_ws, size_t ws_size,
                              hipStream_t stream) {
    const float* x    = (const float*)d_in[0];
    const int*   esrc = (const int*)d_in[1];
    const int*   edst = (const int*)d_in[2];
    const float* ew   = (const float*)d_in[3];
    const float* W1   = (const float*)d_in[4];
    const float* W2   = (const float*)d_in[5];
    float* out = (float*)d_out;

    // Workspace layout (~64.6 MB):
    _Float16* hbuf = (_Float16*)d_ws;                      // N*D fp16 (25.6 MB)
    _Float16* act1 = hbuf + (size_t)N_NODES * D;           // N*D fp16 (25.6 MB)
    int2* ebuf     = (int2*)(act1 + (size_t)N_NODES * D);  // E int2 (12.8 MB), 8B-aligned
    int*  bcnt     = (int*)(ebuf + N_EDGES);               // NBUCK
    int*  boff     = bcnt + NBUCK;                         // NBUCK+1
    int*  gcur     = boff + (NBUCK + 1);                   // NBUCK
    int*  rowptr   = gcur + NBUCK;                         // N+1 ints (0.4 MB)
    char* Wt       = (char*)(rowptr + N_NODES + 8);        // 64 KB (two 32KB blobs)
    (void)ws_size; (void)in_sizes; (void)n_in; (void)out_size;

    // --- W prep + CSR build (graph identical for both layers) ---
    k_wprep<<<32, 256, 0, stream>>>(W1, W2, Wt);
    k_zero <<<(NBUCK + 255) / 256, 256, 0, stream>>>(bcnt, NBUCK);
    k_hist1<<<NWG1, 256, 0, stream>>>(edst, bcnt);
    k_scanN<<<1, 256, 0, stream>>>(bcnt, boff, gcur);
    k_scat1<<<NWG1, 256, 0, stream>>>(esrc, edst, ew, gcur, ebuf);
    k_sortb<<<NBUCK, 512, 0, stream>>>(ebuf, boff, rowptr);

    int gemm_blocks = (N_NODES + 127) / 128;      // 782
    int agg_blocks  = (N_NODES * 64 + 255) / 256; // one wave per node

    // --- layer 1 ---
    k_gemm<false><<<gemm_blocks, 256, 0, stream>>>(x, Wt, hbuf, N_NODES);
    k_agg<true><<<agg_blocks, 256, 0, stream>>>(hbuf, rowptr, ebuf, act1, N_NODES);
    // --- layer 2 ---
    k_gemm<true><<<gemm_blocks, 256, 0, stream>>>(act1, Wt + 32768, hbuf, N_NODES);
    k_agg<false><<<agg_blocks, 256, 0, stream>>>(hbuf, rowptr, ebuf, out, N_NODES);
}

// Round 11
// 237.812 us; speedup vs baseline: 12.3899x; 1.0149x over previous
//
#include <hip/hip_runtime.h>
#include <hip/hip_bf16.h>

#define N_NODES 100000
#define N_EDGES 1600000
#define D 128
#define BSZ 128                         // dst nodes per bucket
#define NBUCK 782                       // ceil(N_NODES / BSZ)
#define EPW 8192                        // edges per WG in hist/scatter
#define NWG1 ((N_EDGES + EPW - 1) / EPW)  // 196
#define CAP 4096                        // LDS edge staging per bucket (mean 2048)
#define OTS 272                         // epilogue LDS tile row stride (bytes)

typedef unsigned int  uint4n  __attribute__((ext_vector_type(4)));
typedef float         float4n __attribute__((ext_vector_type(4)));
typedef _Float16      half8n  __attribute__((ext_vector_type(8)));
typedef _Float16      half4n  __attribute__((ext_vector_type(4)));

// swizzled LDS byte offset for element (row, kb): 256B per row, XOR bits 4-7
#define SWZ(row, kb) (((row) << 8) + ((kb) ^ (((row) & 15) << 4)))

// tanh(x) = 1 - 2/(exp2(2*log2e*x)+1); hw exp2+rcp, abs err ~2e-7.
__device__ __forceinline__ float fast_tanh(float x) {
    float t = __builtin_amdgcn_exp2f(x * 2.885390081777927f);
    return 1.0f - 2.0f * __builtin_amdgcn_rcpf(t + 1.0f);
}

// ---------------- W prep: Wt = fp16(W^T) in the swizzled image ----------------
// Element W[k][c] lands at byte SWZ(c, 2k) of its 32KB blob.
__global__ __launch_bounds__(256) void k_wprep(const float* __restrict__ W1,
                                               const float* __restrict__ W2,
                                               char* __restrict__ Wt) {
    const float* W = (blockIdx.x < 16) ? W1 : W2;
    char* dst = Wt + ((blockIdx.x < 16) ? 0 : 32768);
    int t = (blockIdx.x & 15) * 256 + threadIdx.x;   // 0..4095
    int idx = t * 4;
    int k = idx >> 7, c = idx & 127;
    float4 wv = *(const float4*)&W[idx];
    *(_Float16*)(dst + SWZ(c + 0, k * 2)) = (_Float16)wv.x;
    *(_Float16*)(dst + SWZ(c + 1, k * 2)) = (_Float16)wv.y;
    *(_Float16*)(dst + SWZ(c + 2, k * 2)) = (_Float16)wv.z;
    *(_Float16*)(dst + SWZ(c + 3, k * 2)) = (_Float16)wv.w;
}

// ---------------- stage 0: bucket histogram (LDS-staged, low contention) ----------------

__global__ void k_zero(int* __restrict__ p, int n) {
    int i = blockIdx.x * 256 + threadIdx.x;
    if (i < n) p[i] = 0;
}

__global__ __launch_bounds__(256) void k_hist1(const int* __restrict__ dst,
                                               int* __restrict__ bcnt) {
    __shared__ int h[NBUCK];
    for (int i = threadIdx.x; i < NBUCK; i += 256) h[i] = 0;
    __syncthreads();
    int base = blockIdx.x * EPW;
    int end  = min(base + EPW, N_EDGES);
    for (int i = base + threadIdx.x; i < end; i += 256)
        atomicAdd(&h[dst[i] >> 7], 1);
    __syncthreads();
    for (int i = threadIdx.x; i < NBUCK; i += 256)
        if (h[i]) atomicAdd(&bcnt[i], h[i]);
}

// Single-block exclusive scan over NBUCK counts -> boff & gcur.
__global__ void k_scanN(const int* __restrict__ bcnt, int* __restrict__ boff,
                        int* __restrict__ gcur) {
    __shared__ int tmp[256];
    int tid = threadIdx.x;
    int carry = 0;
    for (int c = 0; c < (NBUCK + 255) / 256; c++) {
        int i = c * 256 + tid;
        int v = (i < NBUCK) ? bcnt[i] : 0;
        tmp[tid] = v;
        __syncthreads();
        int run = v;
        for (int off = 1; off < 256; off <<= 1) {
            int t = (tid >= off) ? tmp[tid - off] : 0;
            __syncthreads();
            run += t;
            tmp[tid] = run;
            __syncthreads();
        }
        int excl = carry + run - v;
        if (i < NBUCK) { boff[i] = excl; gcur[i] = excl; }
        int tot = tmp[255];
        __syncthreads();
        carry += tot;
    }
    if (tid == 0) boff[NBUCK] = N_EDGES;
}

// ---------------- stage 1: bucket scatter (bulk reservation, dense runs) ----------------
// Payload: (src<<7 | dst&127, weight) = 8B.
__global__ __launch_bounds__(256) void k_scat1(const int* __restrict__ src,
                                               const int* __restrict__ dst,
                                               const float* __restrict__ ew,
                                               int* __restrict__ gcur,
                                               int2* __restrict__ ebuf) {
    __shared__ int h[NBUCK];
    __shared__ int rb[NBUCK];
    for (int i = threadIdx.x; i < NBUCK; i += 256) h[i] = 0;
    __syncthreads();
    int base = blockIdx.x * EPW;
    int end  = min(base + EPW, N_EDGES);
    for (int i = base + threadIdx.x; i < end; i += 256)
        atomicAdd(&h[dst[i] >> 7], 1);
    __syncthreads();
    for (int i = threadIdx.x; i < NBUCK; i += 256) {
        int c = h[i];
        if (c) rb[i] = atomicAdd(&gcur[i], c);   // reserve contiguous range
    }
    __syncthreads();
    for (int i = base + threadIdx.x; i < end; i += 256) {
        int d  = dst[i];
        int bk = d >> 7;
        int p  = atomicAdd(&rb[bk], 1);          // LDS int cursor (native, fast)
        ebuf[p] = make_int2((src[i] << 7) | (d & 127), __float_as_int(ew[i]));
    }
}

// ---------------- stage 2: per-bucket counting sort (in-place via LDS) + rowptr ----------------
__global__ __launch_bounds__(512) void k_sortb(int2* __restrict__ ebuf,
                                               const int* __restrict__ boff,
                                               int* __restrict__ rowptr) {
    __shared__ int2 se[CAP];
    __shared__ int cnt[BSZ];
    __shared__ int cur[BSZ];
    int tid = threadIdx.x;
    int b   = blockIdx.x;
    int e0 = boff[b], e1 = boff[b + 1];
    int m  = e1 - e0;
    if (tid < BSZ) cnt[tid] = 0;
    __syncthreads();
    int2 ovf;
    bool hasOvf = false;
    for (int i = tid; i < m; i += 512) {          // all GLOBAL reads happen here
        int2 v = ebuf[e0 + i];
        if (i < CAP) se[i] = v;
        else { ovf = v; hasOvf = true; }          // statistically never (m~2048±45)
        atomicAdd(&cnt[v.x & (BSZ - 1)], 1);
    }
    __syncthreads();
    if (tid < 64) {                               // wave-0 shfl scan of 128 counts
        int a  = cnt[tid * 2], bq = cnt[tid * 2 + 1];
        int s  = a + bq;
        int incl = s;
        #pragma unroll
        for (int off = 1; off < 64; off <<= 1) {
            int t = __shfl_up(incl, off, 64);
            if (tid >= off) incl += t;
        }
        int ex = incl - s;                        // exclusive prefix of this pair
        cur[tid * 2]     = ex;
        cur[tid * 2 + 1] = ex + a;
        int node = b * BSZ + tid * 2;
        if (node     <= N_NODES) rowptr[node]     = e0 + ex;
        if (node + 1 <= N_NODES) rowptr[node + 1] = e0 + ex + a;
    }
    __syncthreads();
    for (int i = tid; i < m && i < CAP; i += 512) {
        int2 v = se[i];
        int p = atomicAdd(&cur[v.x & (BSZ - 1)], 1);
        ebuf[e0 + p] = v;
    }
    if (hasOvf) {
        int p = atomicAdd(&cur[ovf.x & (BSZ - 1)], 1);
        ebuf[e0 + p] = ovf;
    }
}

// ---------------- GEMM (MFMA): H[n x 128](fp16) = X[n x 128] @ W[128 x 128] ----------------
// 1563 blocks x 256 thr (4 waves). Block = 64-row slab, all 128 cols.
// Wave (wr=w>>1, wc=w&1): rows wr*32..+32 (rt=2), cols wc*64..+64 (ct=4).
// W frags direct from global pre-swizzled Wt (L2-broadcast). sA: X slab fp16 swizzled.
// LDS 17.4KB -> occupancy no longer LDS-capped; 2x grid hides stage/epilogue latency.
template<bool XF16>
__global__ __launch_bounds__(256) void k_gemm(const void* __restrict__ Xv,
                                              const char* __restrict__ Wt,
                                              _Float16* __restrict__ H, int n) {
    __shared__ char smem[17408];                  // 64*OTS; staging uses first 16KB
    char* sA = smem;
    int tid  = threadIdx.x;
    int lane = tid & 63, w = tid >> 6;
    int rows0 = blockIdx.x * 64;

    int rb = (w >> 1) * 32;      // wave row base within slab (0/32)
    int cb = (w & 1) * 64;       // wave col base (0/64)
    int lr = lane & 15;          // frag row/col within tile
    int kg = (lane >> 4) * 16;   // k-group byte offset ((lane>>4)*8 halves)

    // preload W frags from GLOBAL pre-swizzled image (same 32KB for all blocks -> L2)
    half8n bw[4][4];
    #pragma unroll
    for (int ks = 0; ks < 4; ks++)
        #pragma unroll
        for (int ct = 0; ct < 4; ct++)
            bw[ks][ct] = *(const half8n*)(Wt + SWZ(cb + ct * 16 + lr, ks * 64 + kg));

    // --- stage A slab (fp16, swizzled): 64 rows x 128 cols ---
    if (XF16) {
        const _Float16* Xh = (const _Float16*)Xv;
        #pragma unroll
        for (int rep = 0; rep < 4; rep++) {
            int ef = rep * 2048 + tid * 8;       // element index r*128+c
            int r = ef >> 7, c = ef & 127;
            int rg = rows0 + r;
            half8n v = half8n(0);
            if (rg < n) v = *(const half8n*)(Xh + (size_t)rg * 128 + c);
            *(half8n*)(sA + SWZ(r, c * 2)) = v;
        }
    } else {
        const float* Xf = (const float*)Xv;
        #pragma unroll
        for (int rep = 0; rep < 8; rep++) {
            int ef = rep * 1024 + tid * 4;
            int r = ef >> 7, c = ef & 127;
            int rg = rows0 + r;
            float4 xv = make_float4(0.f, 0.f, 0.f, 0.f);
            if (rg < n) xv = *(const float4*)(Xf + (size_t)rg * 128 + c);
            half4n hv;
            hv[0] = (_Float16)xv.x; hv[1] = (_Float16)xv.y;
            hv[2] = (_Float16)xv.z; hv[3] = (_Float16)xv.w;
            *(half4n*)(sA + SWZ(r, c * 2)) = hv;
        }
    }
    __syncthreads();

    float4n acc[2][4] = {};
    #pragma unroll
    for (int ks = 0; ks < 4; ks++) {
        half8n af[2];
        #pragma unroll
        for (int rt = 0; rt < 2; rt++)
            af[rt] = *(const half8n*)(sA + SWZ(rb + rt * 16 + lr, ks * 64 + kg));
        #pragma unroll
        for (int rt = 0; rt < 2; rt++)
            #pragma unroll
            for (int ct = 0; ct < 4; ct++)
                acc[rt][ct] = __builtin_amdgcn_mfma_f32_16x16x32_f16(af[rt], bw[ks][ct], acc[rt][ct], 0, 0, 0);
    }

    // --- epilogue: acc -> LDS tile -> coalesced stores ---
    __syncthreads();                              // sA dead, reuse as OT
    char* OT = smem;                              // 64 rows x OTS bytes
    int rloc = rb + (lane >> 4) * 4;              // local row base
    #pragma unroll
    for (int rt = 0; rt < 2; rt++) {
        #pragma unroll
        for (int ct = 0; ct < 4; ct++) {
            int col = cb + ct * 16 + lr;
            #pragma unroll
            for (int r = 0; r < 4; r++)
                *(_Float16*)(OT + (rloc + rt * 16 + r) * OTS + col * 2) = (_Float16)acc[rt][ct][r];
        }
    }
    __syncthreads();
    #pragma unroll
    for (int rep = 0; rep < 4; rep++) {
        int ef = rep * 2048 + tid * 8;
        int r = ef >> 7, c = ef & 127;
        int rg = rows0 + r;
        if (rg < n) {
            half8n v = *(const half8n*)(OT + r * OTS + c * 2);
            *(half8n*)&H[(size_t)rg * 128 + c] = v;
        }
    }
}

// ---------------- Aggregation: out[n] = tanh(sum_e w_e * H[src_e]) ----------------
// One wave per node. 16 lanes cover the 256B fp16 row (16B/lane);
// 4 lane-groups process 4 edges concurrently; shfl_xor(16/32) combines.
template<bool OUTF16>
__global__ __launch_bounds__(256) void k_agg(const _Float16* __restrict__ H,
                                             const int* __restrict__ rowptr,
                                             const int2* __restrict__ ebuf,
                                             void* __restrict__ outv, int n) {
    int wid  = (blockIdx.x * 256 + threadIdx.x) >> 6;
    int lane = threadIdx.x & 63;
    if (wid >= n) return;
    int g = lane >> 4;        // edge slot 0..3
    int c = lane & 15;        // columns c*8 .. c*8+7
    const char* Hc = (const char*)H + (c << 4);   // per-lane column base (16B)
    int e0 = rowptr[wid], e1 = rowptr[wid + 1];
    float acc[8] = {};
    #pragma unroll 2
    for (int eb = e0; eb < e1; eb += 4) {
        int e  = eb + g;
        int ec = (e < e1) ? e : (e1 - 1);        // clamp (branchless; e1>e0 here)
        int2 ed = ebuf[ec];
        float w = (e < e1) ? __int_as_float(ed.y) : 0.f;
        // byte offset of row = src*256 = (ed.x & ~127) << 1
        half8n v = *(const half8n*)(Hc + ((size_t)((unsigned)ed.x & 0xFFFFFF80u) << 1));
        #pragma unroll
        for (int j = 0; j < 8; j++) acc[j] = __builtin_fmaf((float)v[j], w, acc[j]);
    }
    float t[8];
    #pragma unroll
    for (int j = 0; j < 8; j++) {
        float a = acc[j];
        a += __shfl_xor(a, 16, 64);
        a += __shfl_xor(a, 32, 64);
        t[j] = fast_tanh(a);
    }
    if (OUTF16) {
        if (g == 0) {
            half8n hv;
            #pragma unroll
            for (int j = 0; j < 8; j++) hv[j] = (_Float16)t[j];
            uint4n o = *(uint4n*)&hv;
            __builtin_nontemporal_store(o, (uint4n*)((_Float16*)outv + (size_t)wid * 128 + c * 8));
        }
    } else {
        if (g < 2) {
            float4n o;
            o.x = t[g * 4 + 0]; o.y = t[g * 4 + 1];
            o.z = t[g * 4 + 2]; o.w = t[g * 4 + 3];
            __builtin_nontemporal_store(o, (float4n*)((float*)outv + (size_t)wid * 128 + c * 8 + g * 4));
        }
    }
}

// ---------------- launch ----------------

extern "C" void kernel_launch(void* const* d_in, const int* in_sizes, int n_in,
                              void* d_out, int out_size, void* d_ws, size_t ws_size,
                              hipStream_t stream) {
    const float* x    = (const float*)d_in[0];
    const int*   esrc = (const int*)d_in[1];
    const int*   edst = (const int*)d_in[2];
    const float* ew   = (const float*)d_in[3];
    const float* W1   = (const float*)d_in[4];
    const float* W2   = (const float*)d_in[5];
    float* out = (float*)d_out;

    // Workspace layout (~64.6 MB):
    _Float16* hbuf = (_Float16*)d_ws;                      // N*D fp16 (25.6 MB)
    _Float16* act1 = hbuf + (size_t)N_NODES * D;           // N*D fp16 (25.6 MB)
    int2* ebuf     = (int2*)(act1 + (size_t)N_NODES * D);  // E int2 (12.8 MB), 8B-aligned
    int*  bcnt     = (int*)(ebuf + N_EDGES);               // NBUCK
    int*  boff     = bcnt + NBUCK;                         // NBUCK+1
    int*  gcur     = boff + (NBUCK + 1);                   // NBUCK
    int*  rowptr   = gcur + NBUCK;                         // N+1 ints (0.4 MB)
    char* Wt       = (char*)(rowptr + N_NODES + 8);        // 64 KB (two 32KB blobs)
    (void)ws_size; (void)in_sizes; (void)n_in; (void)out_size;

    // --- W prep + CSR build (graph identical for both layers) ---
    k_wprep<<<32, 256, 0, stream>>>(W1, W2, Wt);
    k_zero <<<(NBUCK + 255) / 256, 256, 0, stream>>>(bcnt, NBUCK);
    k_hist1<<<NWG1, 256, 0, stream>>>(edst, bcnt);
    k_scanN<<<1, 256, 0, stream>>>(bcnt, boff, gcur);
    k_scat1<<<NWG1, 256, 0, stream>>>(esrc, edst, ew, gcur, ebuf);
    k_sortb<<<NBUCK, 512, 0, stream>>>(ebuf, boff, rowptr);

    int gemm_blocks = (N_NODES + 63) / 64;        // 1563
    int agg_blocks  = (N_NODES * 64 + 255) / 256; // one wave per node

    // --- layer 1 ---
    k_gemm<false><<<gemm_blocks, 256, 0, stream>>>(x, Wt, hbuf, N_NODES);
    k_agg<true><<<agg_blocks, 256, 0, stream>>>(hbuf, rowptr, ebuf, act1, N_NODES);
    // --- layer 2 ---
    k_gemm<true><<<gemm_blocks, 256, 0, stream>>>(act1, Wt + 32768, hbuf, N_NODES);
    k_agg<false><<<agg_blocks, 256, 0, stream>>>(hbuf, rowptr, ebuf, out, N_NODES);
}

// Round 12
// 231.924 us; speedup vs baseline: 12.7044x; 1.0254x over previous
//
#include <hip/hip_runtime.h>
#include <hip/hip_bf16.h>

#define N_NODES 100000
#define N_EDGES 1600000
#define D 128
#define BSZ 128                         // dst nodes per bucket
#define NBUCK 782                       // ceil(N_NODES / BSZ)
#define EPW 8192                        // edges per WG in hist/scatter
#define NWG1 ((N_EDGES + EPW - 1) / EPW)  // 196
#define CAP 4096                        // LDS edge staging per bucket (mean 2048)
#define OTS 272                         // epilogue LDS tile row stride (bytes)

typedef unsigned int  uint4n  __attribute__((ext_vector_type(4)));
typedef float         float4n __attribute__((ext_vector_type(4)));
typedef _Float16      half8n  __attribute__((ext_vector_type(8)));
typedef _Float16      half4n  __attribute__((ext_vector_type(4)));

// swizzled LDS byte offset for element (row, kb): 256B per row, XOR bits 4-7
#define SWZ(row, kb) (((row) << 8) + ((kb) ^ (((row) & 15) << 4)))

// tanh(x) = 1 - 2/(exp2(2*log2e*x)+1); hw exp2+rcp, abs err ~2e-7.
__device__ __forceinline__ float fast_tanh(float x) {
    float t = __builtin_amdgcn_exp2f(x * 2.885390081777927f);
    return 1.0f - 2.0f * __builtin_amdgcn_rcpf(t + 1.0f);
}

// ---------------- W prep (+ bcnt zero in block 32) ----------------
// Element W[k][c] lands at byte SWZ(c, 2k) of its 32KB blob.
__global__ __launch_bounds__(256) void k_wprep(const float* __restrict__ W1,
                                               const float* __restrict__ W2,
                                               char* __restrict__ Wt,
                                               int* __restrict__ bcnt) {
    if (blockIdx.x == 32) {
        for (int i = threadIdx.x; i < NBUCK; i += 256) bcnt[i] = 0;
        return;
    }
    const float* W = (blockIdx.x < 16) ? W1 : W2;
    char* dst = Wt + ((blockIdx.x < 16) ? 0 : 32768);
    int t = (blockIdx.x & 15) * 256 + threadIdx.x;   // 0..4095
    int idx = t * 4;
    int k = idx >> 7, c = idx & 127;
    float4 wv = *(const float4*)&W[idx];
    *(_Float16*)(dst + SWZ(c + 0, k * 2)) = (_Float16)wv.x;
    *(_Float16*)(dst + SWZ(c + 1, k * 2)) = (_Float16)wv.y;
    *(_Float16*)(dst + SWZ(c + 2, k * 2)) = (_Float16)wv.z;
    *(_Float16*)(dst + SWZ(c + 3, k * 2)) = (_Float16)wv.w;
}

// ---------------- stage 0: bucket histogram (LDS-staged, low contention) ----------------

__global__ __launch_bounds__(256) void k_hist1(const int* __restrict__ dst,
                                               int* __restrict__ bcnt) {
    __shared__ int h[NBUCK];
    for (int i = threadIdx.x; i < NBUCK; i += 256) h[i] = 0;
    __syncthreads();
    int base = blockIdx.x * EPW;
    int end  = min(base + EPW, N_EDGES);
    for (int i = base + threadIdx.x; i < end; i += 256)
        atomicAdd(&h[dst[i] >> 7], 1);
    __syncthreads();
    for (int i = threadIdx.x; i < NBUCK; i += 256)
        if (h[i]) atomicAdd(&bcnt[i], h[i]);
}

// Single-block exclusive scan over NBUCK counts -> boff & gcur.
__global__ void k_scanN(const int* __restrict__ bcnt, int* __restrict__ boff,
                        int* __restrict__ gcur) {
    __shared__ int tmp[256];
    int tid = threadIdx.x;
    int carry = 0;
    for (int c = 0; c < (NBUCK + 255) / 256; c++) {
        int i = c * 256 + tid;
        int v = (i < NBUCK) ? bcnt[i] : 0;
        tmp[tid] = v;
        __syncthreads();
        int run = v;
        for (int off = 1; off < 256; off <<= 1) {
            int t = (tid >= off) ? tmp[tid - off] : 0;
            __syncthreads();
            run += t;
            tmp[tid] = run;
            __syncthreads();
        }
        int excl = carry + run - v;
        if (i < NBUCK) { boff[i] = excl; gcur[i] = excl; }
        int tot = tmp[255];
        __syncthreads();
        carry += tot;
    }
    if (tid == 0) boff[NBUCK] = N_EDGES;
}

// ---------------- stage 1: bucket scatter (bulk reservation, dense runs) ----------------
// Payload: (src<<8 | dst&127, weight) = 8B; src<<8 IS the byte offset of H row.
__global__ __launch_bounds__(256) void k_scat1(const int* __restrict__ src,
                                               const int* __restrict__ dst,
                                               const float* __restrict__ ew,
                                               int* __restrict__ gcur,
                                               int2* __restrict__ ebuf) {
    __shared__ int h[NBUCK];
    __shared__ int rb[NBUCK];
    for (int i = threadIdx.x; i < NBUCK; i += 256) h[i] = 0;
    __syncthreads();
    int base = blockIdx.x * EPW;
    int end  = min(base + EPW, N_EDGES);
    for (int i = base + threadIdx.x; i < end; i += 256)
        atomicAdd(&h[dst[i] >> 7], 1);
    __syncthreads();
    for (int i = threadIdx.x; i < NBUCK; i += 256) {
        int c = h[i];
        if (c) rb[i] = atomicAdd(&gcur[i], c);   // reserve contiguous range
    }
    __syncthreads();
    for (int i = base + threadIdx.x; i < end; i += 256) {
        int d  = dst[i];
        int bk = d >> 7;
        int p  = atomicAdd(&rb[bk], 1);          // LDS int cursor (native, fast)
        ebuf[p] = make_int2((src[i] << 8) | (d & 127), __float_as_int(ew[i]));
    }
}

// ---------------- stage 2: per-bucket counting sort (in-place via LDS) + rowptr ----------------
__global__ __launch_bounds__(512) void k_sortb(int2* __restrict__ ebuf,
                                               const int* __restrict__ boff,
                                               int* __restrict__ rowptr) {
    __shared__ int2 se[CAP];
    __shared__ int cnt[BSZ];
    __shared__ int cur[BSZ];
    int tid = threadIdx.x;
    int b   = blockIdx.x;
    int e0 = boff[b], e1 = boff[b + 1];
    int m  = e1 - e0;
    if (tid < BSZ) cnt[tid] = 0;
    __syncthreads();
    int2 ovf;
    bool hasOvf = false;
    for (int i = tid; i < m; i += 512) {          // all GLOBAL reads happen here
        int2 v = ebuf[e0 + i];
        if (i < CAP) se[i] = v;
        else { ovf = v; hasOvf = true; }          // statistically never (m~2048±45)
        atomicAdd(&cnt[v.x & (BSZ - 1)], 1);
    }
    __syncthreads();
    if (tid < 64) {                               // wave-0 shfl scan of 128 counts
        int a  = cnt[tid * 2], bq = cnt[tid * 2 + 1];
        int s  = a + bq;
        int incl = s;
        #pragma unroll
        for (int off = 1; off < 64; off <<= 1) {
            int t = __shfl_up(incl, off, 64);
            if (tid >= off) incl += t;
        }
        int ex = incl - s;                        // exclusive prefix of this pair
        cur[tid * 2]     = ex;
        cur[tid * 2 + 1] = ex + a;
        int node = b * BSZ + tid * 2;
        if (node     <= N_NODES) rowptr[node]     = e0 + ex;
        if (node + 1 <= N_NODES) rowptr[node + 1] = e0 + ex + a;
    }
    __syncthreads();
    for (int i = tid; i < m && i < CAP; i += 512) {
        int2 v = se[i];
        int p = atomicAdd(&cur[v.x & (BSZ - 1)], 1);
        ebuf[e0 + p] = v;
    }
    if (hasOvf) {
        int p = atomicAdd(&cur[ovf.x & (BSZ - 1)], 1);
        ebuf[e0 + p] = ovf;
    }
}

// ---------------- GEMM (MFMA): H[n x 128](fp16) = X[n x 128] @ W[128 x 128] ----------------
// 1563 blocks x 256 thr (4 waves). Block = 64-row slab, all 128 cols.
// Wave (wr=w>>1, wc=w&1): rows wr*32..+32 (rt=2), cols wc*64..+64 (ct=4).
// W frags loaded per-K-step from global pre-swizzled Wt (L2-hot) -> low VGPR, high occupancy.
template<bool XF16>
__global__ __launch_bounds__(256) void k_gemm(const void* __restrict__ Xv,
                                              const char* __restrict__ Wt,
                                              _Float16* __restrict__ H, int n) {
    __shared__ char smem[17408];                  // 64*OTS; staging uses first 16KB
    char* sA = smem;
    int tid  = threadIdx.x;
    int lane = tid & 63, w = tid >> 6;
    int rows0 = blockIdx.x * 64;

    int rb = (w >> 1) * 32;      // wave row base within slab (0/32)
    int cb = (w & 1) * 64;       // wave col base (0/64)
    int lr = lane & 15;          // frag row/col within tile
    int kg = (lane >> 4) * 16;   // k-group byte offset ((lane>>4)*8 halves)

    // --- stage A slab (fp16, swizzled): 64 rows x 128 cols ---
    if (XF16) {
        const _Float16* Xh = (const _Float16*)Xv;
        #pragma unroll
        for (int rep = 0; rep < 4; rep++) {
            int ef = rep * 2048 + tid * 8;       // element index r*128+c
            int r = ef >> 7, c = ef & 127;
            int rg = rows0 + r;
            half8n v = half8n(0);
            if (rg < n) v = *(const half8n*)(Xh + (size_t)rg * 128 + c);
            *(half8n*)(sA + SWZ(r, c * 2)) = v;
        }
    } else {
        const float* Xf = (const float*)Xv;
        #pragma unroll
        for (int rep = 0; rep < 8; rep++) {
            int ef = rep * 1024 + tid * 4;
            int r = ef >> 7, c = ef & 127;
            int rg = rows0 + r;
            float4 xv = make_float4(0.f, 0.f, 0.f, 0.f);
            if (rg < n) xv = *(const float4*)(Xf + (size_t)rg * 128 + c);
            half4n hv;
            hv[0] = (_Float16)xv.x; hv[1] = (_Float16)xv.y;
            hv[2] = (_Float16)xv.z; hv[3] = (_Float16)xv.w;
            *(half4n*)(sA + SWZ(r, c * 2)) = hv;
        }
    }
    __syncthreads();

    float4n acc[2][4] = {};
    #pragma unroll
    for (int ks = 0; ks < 4; ks++) {
        // W frags for this k-step from L2-hot pre-swizzled image (16 VGPR live)
        half8n bwk[4];
        #pragma unroll
        for (int ct = 0; ct < 4; ct++)
            bwk[ct] = *(const half8n*)(Wt + SWZ(cb + ct * 16 + lr, ks * 64 + kg));
        half8n af[2];
        #pragma unroll
        for (int rt = 0; rt < 2; rt++)
            af[rt] = *(const half8n*)(sA + SWZ(rb + rt * 16 + lr, ks * 64 + kg));
        #pragma unroll
        for (int rt = 0; rt < 2; rt++)
            #pragma unroll
            for (int ct = 0; ct < 4; ct++)
                acc[rt][ct] = __builtin_amdgcn_mfma_f32_16x16x32_f16(af[rt], bwk[ct], acc[rt][ct], 0, 0, 0);
    }

    // --- epilogue: acc -> LDS tile -> coalesced stores ---
    __syncthreads();                              // sA dead, reuse as OT
    char* OT = smem;                              // 64 rows x OTS bytes
    int rloc = rb + (lane >> 4) * 4;              // local row base
    #pragma unroll
    for (int rt = 0; rt < 2; rt++) {
        #pragma unroll
        for (int ct = 0; ct < 4; ct++) {
            int col = cb + ct * 16 + lr;
            #pragma unroll
            for (int r = 0; r < 4; r++)
                *(_Float16*)(OT + (rloc + rt * 16 + r) * OTS + col * 2) = (_Float16)acc[rt][ct][r];
        }
    }
    __syncthreads();
    #pragma unroll
    for (int rep = 0; rep < 4; rep++) {
        int ef = rep * 2048 + tid * 8;
        int r = ef >> 7, c = ef & 127;
        int rg = rows0 + r;
        if (rg < n) {
            half8n v = *(const half8n*)(OT + r * OTS + c * 2);
            *(half8n*)&H[(size_t)rg * 128 + c] = v;
        }
    }
}

// ---------------- Aggregation: out[n] = tanh(sum_e w_e * H[src_e]) ----------------
// One wave per node. 16 lanes cover the 256B fp16 row (16B/lane);
// 4 lane-groups process 4 edges concurrently; shfl_xor(16/32) combines.
// Clean full iterations (no clamp/select) + one masked tail iteration.
template<bool OUTF16>
__global__ __launch_bounds__(256) void k_agg(const _Float16* __restrict__ H,
                                             const int* __restrict__ rowptr,
                                             const int2* __restrict__ ebuf,
                                             void* __restrict__ outv, int n) {
    int wid  = (blockIdx.x * 256 + threadIdx.x) >> 6;
    int lane = threadIdx.x & 63;
    if (wid >= n) return;
    int g = lane >> 4;        // edge slot 0..3
    int c = lane & 15;        // columns c*8 .. c*8+7
    const char* Hc = (const char*)H + (c << 4);   // per-lane column base (16B)
    int e0 = rowptr[wid], e1 = rowptr[wid + 1];
    int m  = e1 - e0;
    int nfull = m >> 2;
    float acc[8] = {};
    const int2* ep = ebuf + e0 + g;
    #pragma unroll 2
    for (int it = 0; it < nfull; ++it, ep += 4) {
        int2 ed = *ep;
        float w = __int_as_float(ed.y);
        // byte offset of row = src*256 = ed.x & ~255 (packed that way)
        half8n v = *(const half8n*)(Hc + (size_t)((unsigned)ed.x & 0xFFFFFF00u));
        #pragma unroll
        for (int j = 0; j < 8; j++) acc[j] = __builtin_fmaf((float)v[j], w, acc[j]);
    }
    if (m & 3) {                                  // masked tail (wave-uniform branch)
        int e  = e0 + nfull * 4 + g;
        int ec = (e < e1) ? e : (e1 - 1);
        int2 ed = ebuf[ec];
        float w = (e < e1) ? __int_as_float(ed.y) : 0.f;
        half8n v = *(const half8n*)(Hc + (size_t)((unsigned)ed.x & 0xFFFFFF00u));
        #pragma unroll
        for (int j = 0; j < 8; j++) acc[j] = __builtin_fmaf((float)v[j], w, acc[j]);
    }
    float t[8];
    #pragma unroll
    for (int j = 0; j < 8; j++) {
        float a = acc[j];
        a += __shfl_xor(a, 16, 64);
        a += __shfl_xor(a, 32, 64);
        t[j] = fast_tanh(a);
    }
    if (OUTF16) {
        if (g == 0) {
            half8n hv;
            #pragma unroll
            for (int j = 0; j < 8; j++) hv[j] = (_Float16)t[j];
            uint4n o = *(uint4n*)&hv;
            __builtin_nontemporal_store(o, (uint4n*)((_Float16*)outv + (size_t)wid * 128 + c * 8));
        }
    } else {
        if (g < 2) {
            float4n o;
            o.x = t[g * 4 + 0]; o.y = t[g * 4 + 1];
            o.z = t[g * 4 + 2]; o.w = t[g * 4 + 3];
            __builtin_nontemporal_store(o, (float4n*)((float*)outv + (size_t)wid * 128 + c * 8 + g * 4));
        }
    }
}

// ---------------- launch ----------------

extern "C" void kernel_launch(void* const* d_in, const int* in_sizes, int n_in,
                              void* d_out, int out_size, void* d_ws, size_t ws_size,
                              hipStream_t stream) {
    const float* x    = (const float*)d_in[0];
    const int*   esrc = (const int*)d_in[1];
    const int*   edst = (const int*)d_in[2];
    const float* ew   = (const float*)d_in[3];
    const float* W1   = (const float*)d_in[4];
    const float* W2   = (const float*)d_in[5];
    float* out = (float*)d_out;

    // Workspace layout (~64.6 MB):
    _Float16* hbuf = (_Float16*)d_ws;                      // N*D fp16 (25.6 MB)
    _Float16* act1 = hbuf + (size_t)N_NODES * D;           // N*D fp16 (25.6 MB)
    int2* ebuf     = (int2*)(act1 + (size_t)N_NODES * D);  // E int2 (12.8 MB), 8B-aligned
    int*  bcnt     = (int*)(ebuf + N_EDGES);               // NBUCK
    int*  boff     = bcnt + NBUCK;                         // NBUCK+1
    int*  gcur     = boff + (NBUCK + 1);                   // NBUCK
    int*  rowptr   = gcur + NBUCK;                         // N+1 ints (0.4 MB)
    char* Wt       = (char*)(rowptr + N_NODES + 8);        // 64 KB (two 32KB blobs)
    (void)ws_size; (void)in_sizes; (void)n_in; (void)out_size;

    // --- W prep (+bcnt zero) + CSR build (graph identical for both layers) ---
    k_wprep<<<33, 256, 0, stream>>>(W1, W2, Wt, bcnt);
    k_hist1<<<NWG1, 256, 0, stream>>>(edst, bcnt);
    k_scanN<<<1, 256, 0, stream>>>(bcnt, boff, gcur);
    k_scat1<<<NWG1, 256, 0, stream>>>(esrc, edst, ew, gcur, ebuf);
    k_sortb<<<NBUCK, 512, 0, stream>>>(ebuf, boff, rowptr);

    int gemm_blocks = (N_NODES + 63) / 64;        // 1563
    int agg_blocks  = (N_NODES * 64 + 255) / 256; // one wave per node

    // --- layer 1 ---
    k_gemm<false><<<gemm_blocks, 256, 0, stream>>>(x, Wt, hbuf, N_NODES);
    k_agg<true><<<agg_blocks, 256, 0, stream>>>(hbuf, rowptr, ebuf, act1, N_NODES);
    // --- layer 2 ---
    k_gemm<true><<<gemm_blocks, 256, 0, stream>>>(act1, Wt + 32768, hbuf, N_NODES);
    k_agg<false><<<agg_blocks, 256, 0, stream>>>(hbuf, rowptr, ebuf, out, N_NODES);
}